// Round 1
// baseline (319.592 us; speedup 1.0000x reference)
//
#include <hip/hip_runtime.h>
#include <hip/hip_bf16.h>
#include <stdint.h>

// Problem constants
#define TLEN 2048
#define NHEAD 16
#define CD 1024
#define HDIM 64

typedef __attribute__((ext_vector_type(4))) float f32x4;
typedef __attribute__((ext_vector_type(8))) short s16x8;
typedef __attribute__((ext_vector_type(8))) unsigned short u16x8;
typedef __attribute__((ext_vector_type(4))) unsigned short u16x4;

typedef __attribute__((address_space(1))) const unsigned int global_u32;
typedef __attribute__((address_space(3))) unsigned int lds_u32;

__device__ __forceinline__ void gl_lds16(const void* g, void* l) {
  __builtin_amdgcn_global_load_lds((global_u32*)g, (lds_u32*)l, 16, 0, 0);
}

__device__ __forceinline__ unsigned short f2bf(float x) {
  unsigned int u = __float_as_uint(x);
  u += 0x7fffu + ((u >> 16) & 1u);   // RTNE; inputs finite
  return (unsigned short)(u >> 16);
}

__device__ __forceinline__ f32x4 mfma_bf16(s16x8 a, s16x8 b, f32x4 c) {
  return __builtin_amdgcn_mfma_f32_16x16x32_bf16(a, b, c, 0, 0, 0);
}

// ---------------- fp32 -> bf16 cast, 8 elems/thread ----------------
__global__ __launch_bounds__(256) void cvt_bf16(const float* __restrict__ src,
                                                unsigned short* __restrict__ dst) {
  int i = (blockIdx.x * 256 + threadIdx.x) * 8;
  float4 a = *(const float4*)(src + i);
  float4 b = *(const float4*)(src + i + 4);
  u16x8 o;
  o[0] = f2bf(a.x); o[1] = f2bf(a.y); o[2] = f2bf(a.z); o[3] = f2bf(a.w);
  o[4] = f2bf(b.x); o[5] = f2bf(b.y); o[6] = f2bf(b.z); o[7] = f2bf(b.w);
  *(u16x8*)(dst + i) = o;
}

// ---------------- GEMM: C[M][N] = A[M][K] * Bw[N][K]^T + bias ----------------
// SPLIT=1: N=3072 QKV output -> Q,K rows into qk_out [M][2048], V transposed
//          into vt_out [b*1024 + h*64 + d][T].
// SPLIT=0: fp32 output Cf [M][N].
#define BM 128
#define BN 128
#define BKG 64

template <int SPLIT>
__global__ __launch_bounds__(256) void gemm_bt(
    const unsigned short* __restrict__ A, const unsigned short* __restrict__ Bw,
    const float* __restrict__ bias, float* __restrict__ Cf,
    unsigned short* __restrict__ qk_out, unsigned short* __restrict__ vt_out,
    int M, int N, int K) {
  __shared__ char lds[(BM + BN) * BKG * 2];   // 32 KiB
  char* aL = lds;
  char* bL = lds + BM * BKG * 2;
  const int tid = threadIdx.x;
  const int w = tid >> 6, l = tid & 63, l15 = l & 15, l4 = l >> 4;
  const int wr = w >> 1, wc = w & 1;
  const int brow = blockIdx.y * BM, bcol = blockIdx.x * BN;

  f32x4 z4 = {0.f, 0.f, 0.f, 0.f};
  f32x4 acc[4][4];
#pragma unroll
  for (int m = 0; m < 4; ++m)
#pragma unroll
    for (int n = 0; n < 4; ++n) acc[m][n] = z4;

  const unsigned short* Ab = A + (size_t)brow * K;
  const unsigned short* Bb = Bw + (size_t)bcol * K;

  for (int k0 = 0; k0 < K; k0 += BKG) {
    __syncthreads();
#pragma unroll
    for (int i = 0; i < 4; ++i) {   // 1024 chunks per tile, 4 per thread
      int ch = i * 256 + tid;
      int r = ch >> 3, c = ch & 7;
      int cs = (c ^ (r & 7)) * 8;   // pre-swizzled source -> swizzled LDS content
      gl_lds16(Ab + (size_t)r * K + k0 + cs, aL + ch * 16);
      gl_lds16(Bb + (size_t)r * K + k0 + cs, bL + ch * 16);
    }
    __syncthreads();   // compiler drains vmcnt before s_barrier
#pragma unroll
    for (int kk = 0; kk < 2; ++kk) {
      s16x8 af[4], bfr[4];
#pragma unroll
      for (int m = 0; m < 4; ++m) {
        int r = wr * 64 + m * 16 + l15;
        af[m] = *(const s16x8*)(aL + r * (BKG * 2) +
                                ((kk * 64 + l4 * 16) ^ ((r & 7) << 4)));
      }
#pragma unroll
      for (int n = 0; n < 4; ++n) {
        int r = wc * 64 + n * 16 + l15;
        bfr[n] = *(const s16x8*)(bL + r * (BKG * 2) +
                                 ((kk * 64 + l4 * 16) ^ ((r & 7) << 4)));
      }
#pragma unroll
      for (int m = 0; m < 4; ++m)
#pragma unroll
        for (int n = 0; n < 4; ++n) acc[m][n] = mfma_bf16(af[m], bfr[n], acc[m][n]);
    }
  }

  // epilogue: D row = (l>>4)*4 + reg, col = l&15  (m89-verified layout)
#pragma unroll
  for (int m = 0; m < 4; ++m) {
    int row0 = brow + wr * 64 + m * 16 + l4 * 4;
#pragma unroll
    for (int n = 0; n < 4; ++n) {
      int col = bcol + wc * 64 + n * 16 + l15;
      float bs = bias[col];
      if (SPLIT == 0) {
#pragma unroll
        for (int r = 0; r < 4; ++r)
          Cf[(size_t)(row0 + r) * N + col] = acc[m][n][r] + bs;
      } else {
        if (col < 2 * CD) {   // Q or K: row-major [M][2048]
#pragma unroll
          for (int r = 0; r < 4; ++r)
            qk_out[(size_t)(row0 + r) * (2 * CD) + col] = f2bf(acc[m][n][r] + bs);
        } else {              // V: transposed [b*1024 + h*64+d][T], 8B packed
          int cc = col - 2 * CD;
          int b_ = row0 >> 11;
          int t = row0 & (TLEN - 1);
          u16x4 pk;
#pragma unroll
          for (int r = 0; r < 4; ++r) pk[r] = f2bf(acc[m][n][r] + bs);
          *(u16x4*)(vt_out + (size_t)(b_ * CD + cc) * TLEN + t) = pk;
        }
      }
    }
  }
}

// ---------------- flash attention ----------------
// grid (32 q-tiles, 64 bh). 4 waves/block, wave w owns q rows [w*16, w*16+16).
__global__ __launch_bounds__(256) void attn_fwd(
    const unsigned short* __restrict__ qk,   // [B*T][2048] bf16: Q | K
    const unsigned short* __restrict__ vt,   // [B*H*64][2048] = V^T per head
    unsigned short* __restrict__ ctx) {      // [B*T][1024]
  __shared__ char k_lds[64 * 128];          // K tile [kv][d], swizzled
  __shared__ char v_lds[64 * 128];          // V^T tile [d][kv], swizzled
  __shared__ char p_lds[4 * 16 * 128];      // per-wave P [16][64], swizzled

  const int qi = blockIdx.x;
  const int bh = blockIdx.y;
  const int b = bh >> 4, h = bh & 15;
  const int tid = threadIdx.x;
  const int w = tid >> 6, l = tid & 63, l15 = l & 15, l4 = l >> 4;

  // Q fragments: A[q=l&15][d = l4*8+j], two d-chunks of 32
  const unsigned short* qrow =
      qk + (size_t)(b * TLEN + qi * 64 + w * 16 + l15) * (2 * CD) + h * HDIM;
  s16x8 qf0 = *(const s16x8*)(qrow + l4 * 8);
  s16x8 qf1 = *(const s16x8*)(qrow + 32 + l4 * 8);

  const unsigned short* Kg = qk + (size_t)b * TLEN * (2 * CD) + CD + h * HDIM;
  const unsigned short* Vg = vt + (size_t)bh * HDIM * TLEN;

  f32x4 z4 = {0.f, 0.f, 0.f, 0.f};
  f32x4 acc_o[4];
#pragma unroll
  for (int dc = 0; dc < 4; ++dc) acc_o[dc] = z4;
  float m_r[4], l_r[4];
#pragma unroll
  for (int r = 0; r < 4; ++r) { m_r[r] = -3.0e38f; l_r[r] = 0.f; }

  const float SC2 = 0.18033688011112042f;   // (1/sqrt(64)) * log2(e)
  char* pw = p_lds + w * 2048;

  for (int kt = 0; kt <= qi; ++kt) {
    __syncthreads();   // protect K/V LDS from previous iteration's readers
#pragma unroll
    for (int i = 0; i < 2; ++i) {   // 512 chunks each for K and V^T
      int ch = i * 256 + tid;
      int r = ch >> 3, c = ch & 7;
      int cs = (c ^ (r & 7)) * 8;
      gl_lds16(Kg + (size_t)(kt * 64 + r) * (2 * CD) + cs, k_lds + ch * 16);
      gl_lds16(Vg + (size_t)r * TLEN + kt * 64 + cs, v_lds + ch * 16);
    }
    __syncthreads();

    // S = Q K^T (raw, scale folded into exp2)
    f32x4 s[4];
#pragma unroll
    for (int n = 0; n < 4; ++n) {
      int r = n * 16 + l15;
      int sw = (r & 7) << 4;
      s16x8 kf0 = *(const s16x8*)(k_lds + r * 128 + ((l4 * 16) ^ sw));
      s16x8 kf1 = *(const s16x8*)(k_lds + r * 128 + ((64 + l4 * 16) ^ sw));
      f32x4 z = z4;
      z = mfma_bf16(qf0, kf0, z);
      z = mfma_bf16(qf1, kf1, z);
      s[n] = z;
    }

    if (kt == qi) {   // causal mask on the diagonal tile only
#pragma unroll
      for (int n = 0; n < 4; ++n) {
        int kl = n * 16 + l15;
#pragma unroll
        for (int r = 0; r < 4; ++r) {
          int ql = w * 16 + l4 * 4 + r;
          if (kl > ql) s[n][r] = -3.0e38f;
        }
      }
    }

    // tile row-max (rows live in regs; 16 lanes of an l4-group share rows)
    float tm[4];
#pragma unroll
    for (int r = 0; r < 4; ++r)
      tm[r] = fmaxf(fmaxf(s[0][r], s[1][r]), fmaxf(s[2][r], s[3][r]));
#pragma unroll
    for (int off = 1; off < 16; off <<= 1)
#pragma unroll
      for (int r = 0; r < 4; ++r) tm[r] = fmaxf(tm[r], __shfl_xor(tm[r], off));

    float corr[4];
#pragma unroll
    for (int r = 0; r < 4; ++r) {
      float mn = fmaxf(m_r[r], tm[r]);
      corr[r] = __builtin_amdgcn_exp2f((m_r[r] - mn) * SC2);
      m_r[r] = mn;
    }

    // P = exp2((S - m)*SC2); write bf16 P to wave-private LDS (swizzled)
    float ts[4] = {0.f, 0.f, 0.f, 0.f};
#pragma unroll
    for (int n = 0; n < 4; ++n)
#pragma unroll
      for (int r = 0; r < 4; ++r) {
        float p = __builtin_amdgcn_exp2f((s[n][r] - m_r[r]) * SC2);
        ts[r] += p;
        int prow = l4 * 4 + r;
        *(unsigned short*)(pw + prow * 128 +
                           ((n * 32 + l15 * 2) ^ ((prow & 7) << 4))) = f2bf(p);
      }
#pragma unroll
    for (int off = 1; off < 16; off <<= 1)
#pragma unroll
      for (int r = 0; r < 4; ++r) ts[r] += __shfl_xor(ts[r], off);
#pragma unroll
    for (int r = 0; r < 4; ++r) l_r[r] = l_r[r] * corr[r] + ts[r];
#pragma unroll
    for (int dc = 0; dc < 4; ++dc)
#pragma unroll
      for (int r = 0; r < 4; ++r) acc_o[dc][r] *= corr[r];

    // P writes are wave-private; DS pipe is in-order per wave, just drain
    asm volatile("s_waitcnt lgkmcnt(0)" ::: "memory");

    // O += P V  (A = P[16q][32k], B = V[k][d] read from V^T tile rows)
#pragma unroll
    for (int kc = 0; kc < 2; ++kc) {
      s16x8 pf = *(const s16x8*)(pw + l15 * 128 +
                                 ((kc * 64 + l4 * 16) ^ ((l15 & 7) << 4)));
#pragma unroll
      for (int dc = 0; dc < 4; ++dc) {
        int rd = dc * 16 + l15;
        s16x8 vf = *(const s16x8*)(v_lds + rd * 128 +
                                   ((kc * 64 + l4 * 16) ^ ((rd & 7) << 4)));
        acc_o[dc] = mfma_bf16(pf, vf, acc_o[dc]);
      }
    }
  }

  // normalize + write ctx (bf16)
#pragma unroll
  for (int r = 0; r < 4; ++r) {
    int qg = qi * 64 + w * 16 + l4 * 4 + r;
    float inv = 1.0f / l_r[r];
    size_t base = (size_t)(b * TLEN + qg) * CD + h * HDIM;
#pragma unroll
    for (int dc = 0; dc < 4; ++dc)
      ctx[base + dc * 16 + l15] = f2bf(acc_o[dc][r] * inv);
  }
}

// ---------------- launch ----------------
extern "C" void kernel_launch(void* const* d_in, const int* in_sizes, int n_in,
                              void* d_out, int out_size, void* d_ws, size_t ws_size,
                              hipStream_t stream) {
  const float* X  = (const float*)d_in[0];   // [4,2048,1024]
  const float* Wq = (const float*)d_in[1];   // [3072,1024]
  const float* bq = (const float*)d_in[2];   // [3072]
  const float* Wo = (const float*)d_in[3];   // [1024,1024]
  const float* bo = (const float*)d_in[4];   // [1024]
  float* out = (float*)d_out;

  char* ws = (char*)d_ws;
  unsigned short* Xb  = (unsigned short*)ws;                       // 16.78 MB
  unsigned short* Wqb = (unsigned short*)(ws + 16777216);          //  6.29 MB
  unsigned short* Wob = (unsigned short*)(ws + 23068672);          //  2.10 MB
  unsigned short* QK  = (unsigned short*)(ws + 25165824);          // 33.55 MB
  unsigned short* Vt  = (unsigned short*)(ws + 58720256);          // 16.78 MB
  unsigned short* Ctx = Xb;   // alias: Xb dead after QKV GEMM     // total 75.5 MB

  cvt_bf16<<<4096, 256, 0, stream>>>(X, Xb);
  cvt_bf16<<<1536, 256, 0, stream>>>(Wq, Wqb);
  cvt_bf16<<<512, 256, 0, stream>>>(Wo, Wob);

  gemm_bt<1><<<dim3(24, 64), 256, 0, stream>>>(Xb, Wqb, bq, nullptr, QK, Vt,
                                               8192, 3072, 1024);
  attn_fwd<<<dim3(32, 64), 256, 0, stream>>>(QK, Vt, Ctx);
  gemm_bt<0><<<dim3(8, 64), 256, 0, stream>>>(Ctx, Wob, bo, out, nullptr, nullptr,
                                              8192, 1024, 1024);
}

// Round 2
// 231.451 us; speedup vs baseline: 1.3808x; 1.3808x over previous
//
#include <hip/hip_runtime.h>
#include <hip/hip_bf16.h>
#include <stdint.h>

// Problem constants
#define TLEN 2048
#define NHEAD 16
#define CD 1024
#define HDIM 64

typedef __attribute__((ext_vector_type(4))) float f32x4;
typedef __attribute__((ext_vector_type(8))) short s16x8;
typedef __attribute__((ext_vector_type(8))) unsigned short u16x8;
typedef __attribute__((ext_vector_type(4))) unsigned short u16x4;

typedef __attribute__((address_space(1))) const unsigned int global_u32;
typedef __attribute__((address_space(3))) unsigned int lds_u32;

__device__ __forceinline__ void gl_lds16(const void* g, void* l) {
  __builtin_amdgcn_global_load_lds((global_u32*)g, (lds_u32*)l, 16, 0, 0);
}

__device__ __forceinline__ unsigned short f2bf(float x) {
  unsigned int u = __float_as_uint(x);
  u += 0x7fffu + ((u >> 16) & 1u);   // RTNE; inputs finite
  return (unsigned short)(u >> 16);
}

__device__ __forceinline__ f32x4 mfma_bf16(s16x8 a, s16x8 b, f32x4 c) {
  return __builtin_amdgcn_mfma_f32_16x16x32_bf16(a, b, c, 0, 0, 0);
}

// ---------------- fp32 -> bf16 cast, 8 elems/thread ----------------
__global__ __launch_bounds__(256) void cvt_bf16(const float* __restrict__ src,
                                                unsigned short* __restrict__ dst) {
  int i = (blockIdx.x * 256 + threadIdx.x) * 8;
  float4 a = *(const float4*)(src + i);
  float4 b = *(const float4*)(src + i + 4);
  u16x8 o;
  o[0] = f2bf(a.x); o[1] = f2bf(a.y); o[2] = f2bf(a.z); o[3] = f2bf(a.w);
  o[4] = f2bf(b.x); o[5] = f2bf(b.y); o[6] = f2bf(b.z); o[7] = f2bf(b.w);
  *(u16x8*)(dst + i) = o;
}

// ---------------- GEMM: C[M][N] = A[M][K] * Bw[N][K]^T + bias ----------------
#define BM 128
#define BN 128
#define BKG 64

template <int SPLIT>
__global__ __launch_bounds__(256) void gemm_bt(
    const unsigned short* __restrict__ A, const unsigned short* __restrict__ Bw,
    const float* __restrict__ bias, float* __restrict__ Cf,
    unsigned short* __restrict__ qk_out, unsigned short* __restrict__ vt_out,
    int M, int N, int K) {
  __shared__ char lds[(BM + BN) * BKG * 2];   // 32 KiB
  char* aL = lds;
  char* bL = lds + BM * BKG * 2;
  const int tid = threadIdx.x;
  const int w = tid >> 6, l = tid & 63, l15 = l & 15, l4 = l >> 4;
  const int wr = w >> 1, wc = w & 1;
  const int brow = blockIdx.y * BM, bcol = blockIdx.x * BN;

  f32x4 z4 = {0.f, 0.f, 0.f, 0.f};
  f32x4 acc[4][4];
#pragma unroll
  for (int m = 0; m < 4; ++m)
#pragma unroll
    for (int n = 0; n < 4; ++n) acc[m][n] = z4;

  const unsigned short* Ab = A + (size_t)brow * K;
  const unsigned short* Bb = Bw + (size_t)bcol * K;

  for (int k0 = 0; k0 < K; k0 += BKG) {
    __syncthreads();
#pragma unroll
    for (int i = 0; i < 4; ++i) {
      int ch = i * 256 + tid;
      int r = ch >> 3, c = ch & 7;
      int cs = (c ^ (r & 7)) * 8;
      gl_lds16(Ab + (size_t)r * K + k0 + cs, aL + ch * 16);
      gl_lds16(Bb + (size_t)r * K + k0 + cs, bL + ch * 16);
    }
    __syncthreads();
#pragma unroll
    for (int kk = 0; kk < 2; ++kk) {
      s16x8 af[4], bfr[4];
#pragma unroll
      for (int m = 0; m < 4; ++m) {
        int r = wr * 64 + m * 16 + l15;
        af[m] = *(const s16x8*)(aL + r * (BKG * 2) +
                                ((kk * 64 + l4 * 16) ^ ((r & 7) << 4)));
      }
#pragma unroll
      for (int n = 0; n < 4; ++n) {
        int r = wc * 64 + n * 16 + l15;
        bfr[n] = *(const s16x8*)(bL + r * (BKG * 2) +
                                 ((kk * 64 + l4 * 16) ^ ((r & 7) << 4)));
      }
#pragma unroll
      for (int m = 0; m < 4; ++m)
#pragma unroll
        for (int n = 0; n < 4; ++n) acc[m][n] = mfma_bf16(af[m], bfr[n], acc[m][n]);
    }
  }

#pragma unroll
  for (int m = 0; m < 4; ++m) {
    int row0 = brow + wr * 64 + m * 16 + l4 * 4;
#pragma unroll
    for (int n = 0; n < 4; ++n) {
      int col = bcol + wc * 64 + n * 16 + l15;
      float bs = bias[col];
      if (SPLIT == 0) {
#pragma unroll
        for (int r = 0; r < 4; ++r)
          Cf[(size_t)(row0 + r) * N + col] = acc[m][n][r] + bs;
      } else {
        if (col < 2 * CD) {
#pragma unroll
          for (int r = 0; r < 4; ++r)
            qk_out[(size_t)(row0 + r) * (2 * CD) + col] = f2bf(acc[m][n][r] + bs);
        } else {
          int cc = col - 2 * CD;
          int b_ = row0 >> 11;
          int t = row0 & (TLEN - 1);
          u16x4 pk;
#pragma unroll
          for (int r = 0; r < 4; ++r) pk[r] = f2bf(acc[m][n][r] + bs);
          *(u16x4*)(vt_out + (size_t)(b_ * CD + cc) * TLEN + t) = pk;
        }
      }
    }
  }
}

// ---------------- flash attention (paired q-tiles, 2-deep KV pipeline) -------
// grid (16 pair-slots, 64 bh). Block j handles q-tiles j and 31-j: uniform
// 33 tile-iters/block. 1024 blocks x 40KB LDS = 4 blocks/CU, all resident.
// K/V double-buffered; raw s_barrier + counted vmcnt keeps next tile's
// global_load_lds in flight under current tile's compute (T3/T4).
__global__ __launch_bounds__(256) void attn_fwd(
    const unsigned short* __restrict__ qk,   // [B*T][2048] bf16: Q | K
    const unsigned short* __restrict__ vt,   // [B*H*64][2048] = V^T per head
    unsigned short* __restrict__ ctx) {      // [B*T][1024]
  __shared__ char k_lds[2 * 64 * 128];      // K tiles [kv][d], swizzled
  __shared__ char v_lds[2 * 64 * 128];      // V^T tiles [d][kv], swizzled
  __shared__ char p_lds[4 * 16 * 128];      // per-wave P [16][64], swizzled

  const int jp = blockIdx.x;                // 0..15
  const int bh = blockIdx.y;
  const int b = bh >> 4, h = bh & 15;
  const int tid = threadIdx.x;
  const int w = tid >> 6, l = tid & 63, l15 = l & 15, l4 = l >> 4;

  const unsigned short* Kg = qk + (size_t)b * TLEN * (2 * CD) + CD + h * HDIM;
  const unsigned short* Vg = vt + (size_t)bh * HDIM * TLEN;

  const float SC2 = 0.18033688011112042f;   // (1/sqrt(64)) * log2(e)
  char* pw = p_lds + w * 2048;

  s16x8 onesf;                              // bf16 1.0 broadcast B-fragment
#pragma unroll
  for (int j = 0; j < 8; ++j) onesf[j] = (short)0x3F80;

  f32x4 z4 = {0.f, 0.f, 0.f, 0.f};

  for (int seg = 0; seg < 2; ++seg) {
    const int qi = seg == 0 ? jp : 31 - jp;
    const int nt = qi + 1;

    // Q fragments: A[q=l&15][d = l4*8+j], two d-chunks of 32
    const unsigned short* qrow =
        qk + (size_t)(b * TLEN + qi * 64 + w * 16 + l15) * (2 * CD) + h * HDIM;
    s16x8 qf0 = *(const s16x8*)(qrow + l4 * 8);
    s16x8 qf1 = *(const s16x8*)(qrow + 32 + l4 * 8);

    f32x4 acc_o[4];
#pragma unroll
    for (int dc = 0; dc < 4; ++dc) acc_o[dc] = z4;
    f32x4 acc_l = z4;                       // softmax denominator (ones-MFMA)
    float m_r[4];
#pragma unroll
    for (int r = 0; r < 4; ++r) m_r[r] = -3.0e38f;

    // stage helper: 4 gl_lds16 per thread (2 K + 2 V^T)
    auto stage = [&](int buf, int kt) {
#pragma unroll
      for (int i = 0; i < 2; ++i) {
        int ch = i * 256 + tid;
        int r = ch >> 3, c = ch & 7;
        int cs = (c ^ (r & 7)) * 8;
        gl_lds16(Kg + (size_t)(kt * 64 + r) * (2 * CD) + cs,
                 k_lds + buf * 8192 + ch * 16);
        gl_lds16(Vg + (size_t)r * TLEN + kt * 64 + cs,
                 v_lds + buf * 8192 + ch * 16);
      }
    };

    __builtin_amdgcn_s_barrier();           // seg boundary: both bufs free
    stage(0, 0);                            // prologue
    int cur = 0;

    for (int kt = 0; kt < nt; ++kt) {
      __builtin_amdgcn_s_barrier();         // all waves done reading buf^1
      if (kt + 1 < nt) {
        stage(cur ^ 1, kt + 1);             // prefetch next tile
        asm volatile("s_waitcnt vmcnt(4)" ::: "memory");  // cur's 4 loads done
      } else {
        asm volatile("s_waitcnt vmcnt(0)" ::: "memory");
      }
      __builtin_amdgcn_sched_barrier(0);
      __builtin_amdgcn_s_barrier();         // buf[cur] visible to all waves
      __builtin_amdgcn_sched_barrier(0);

      const char* kb = k_lds + cur * 8192;
      const char* vb = v_lds + cur * 8192;

      // S = Q K^T (raw; scale folded into exp2)
      f32x4 s[4];
#pragma unroll
      for (int n = 0; n < 4; ++n) {
        int r = n * 16 + l15;
        int sw = (r & 7) << 4;
        s16x8 kf0 = *(const s16x8*)(kb + r * 128 + ((l4 * 16) ^ sw));
        s16x8 kf1 = *(const s16x8*)(kb + r * 128 + ((64 + l4 * 16) ^ sw));
        f32x4 z = z4;
        z = mfma_bf16(qf0, kf0, z);
        z = mfma_bf16(qf1, kf1, z);
        s[n] = z;
      }

      if (kt == qi) {                       // causal mask, diagonal tile only
#pragma unroll
        for (int n = 0; n < 4; ++n) {
          int kl = n * 16 + l15;
#pragma unroll
          for (int r = 0; r < 4; ++r) {
            int ql = w * 16 + l4 * 4 + r;
            if (kl > ql) s[n][r] = -3.0e38f;
          }
        }
      }

      // tile row-max across the 16 lanes sharing rows
      float tm[4];
#pragma unroll
      for (int r = 0; r < 4; ++r)
        tm[r] = fmaxf(fmaxf(s[0][r], s[1][r]), fmaxf(s[2][r], s[3][r]));
#pragma unroll
      for (int off = 1; off < 16; off <<= 1)
#pragma unroll
        for (int r = 0; r < 4; ++r) tm[r] = fmaxf(tm[r], __shfl_xor(tm[r], off));

      float corr[4];
#pragma unroll
      for (int r = 0; r < 4; ++r) {
        float mn = fmaxf(m_r[r], tm[r]);
        corr[r] = __builtin_amdgcn_exp2f((m_r[r] - mn) * SC2);
        m_r[r] = mn;
      }

      // P = exp2((S - m)*SC2) -> bf16 -> wave-private swizzled LDS
#pragma unroll
      for (int n = 0; n < 4; ++n)
#pragma unroll
        for (int r = 0; r < 4; ++r) {
          float p = __builtin_amdgcn_exp2f((s[n][r] - m_r[r]) * SC2);
          int prow = l4 * 4 + r;
          *(unsigned short*)(pw + prow * 128 +
                             ((n * 32 + l15 * 2) ^ ((prow & 7) << 4))) = f2bf(p);
        }

      // rescale running accumulators (O and denominator)
#pragma unroll
      for (int r = 0; r < 4; ++r) {
        acc_l[r] *= corr[r];
#pragma unroll
        for (int dc = 0; dc < 4; ++dc) acc_o[dc][r] *= corr[r];
      }

      // P writes are wave-private; DS pipe is in-order per wave, just drain
      asm volatile("s_waitcnt lgkmcnt(0)" ::: "memory");
      __builtin_amdgcn_sched_barrier(0);

      // O += P V ; denominator += P * ones (row-sum via matrix pipe)
#pragma unroll
      for (int kc = 0; kc < 2; ++kc) {
        s16x8 pf = *(const s16x8*)(pw + l15 * 128 +
                                   ((kc * 64 + l4 * 16) ^ ((l15 & 7) << 4)));
        acc_l = mfma_bf16(pf, onesf, acc_l);
#pragma unroll
        for (int dc = 0; dc < 4; ++dc) {
          int rd = dc * 16 + l15;
          s16x8 vf = *(const s16x8*)(vb + rd * 128 +
                                     ((kc * 64 + l4 * 16) ^ ((rd & 7) << 4)));
          acc_o[dc] = mfma_bf16(pf, vf, acc_o[dc]);
        }
      }
      cur ^= 1;
    }

    // normalize + write ctx (bf16)
#pragma unroll
    for (int r = 0; r < 4; ++r) {
      int qg = qi * 64 + w * 16 + l4 * 4 + r;
      float inv = 1.0f / acc_l[r];
      size_t base = (size_t)(b * TLEN + qg) * CD + h * HDIM;
#pragma unroll
      for (int dc = 0; dc < 4; ++dc)
        ctx[base + dc * 16 + l15] = f2bf(acc_o[dc][r] * inv);
    }
  }
}

// ---------------- launch ----------------
extern "C" void kernel_launch(void* const* d_in, const int* in_sizes, int n_in,
                              void* d_out, int out_size, void* d_ws, size_t ws_size,
                              hipStream_t stream) {
  const float* X  = (const float*)d_in[0];   // [4,2048,1024]
  const float* Wq = (const float*)d_in[1];   // [3072,1024]
  const float* bq = (const float*)d_in[2];   // [3072]
  const float* Wo = (const float*)d_in[3];   // [1024,1024]
  const float* bo = (const float*)d_in[4];   // [1024]
  float* out = (float*)d_out;

  char* ws = (char*)d_ws;
  unsigned short* Xb  = (unsigned short*)ws;                       // 16.78 MB
  unsigned short* Wqb = (unsigned short*)(ws + 16777216);          //  6.29 MB
  unsigned short* Wob = (unsigned short*)(ws + 23068672);          //  2.10 MB
  unsigned short* QK  = (unsigned short*)(ws + 25165824);          // 33.55 MB
  unsigned short* Vt  = (unsigned short*)(ws + 58720256);          // 16.78 MB
  unsigned short* Ctx = Xb;   // alias: Xb dead after QKV GEMM     // total 75.5 MB

  cvt_bf16<<<4096, 256, 0, stream>>>(X, Xb);
  cvt_bf16<<<1536, 256, 0, stream>>>(Wq, Wqb);
  cvt_bf16<<<512, 256, 0, stream>>>(Wo, Wob);

  gemm_bt<1><<<dim3(24, 64), 256, 0, stream>>>(Xb, Wqb, bq, nullptr, QK, Vt,
                                               8192, 3072, 1024);
  attn_fwd<<<dim3(16, 64), 256, 0, stream>>>(QK, Vt, Ctx);
  gemm_bt<0><<<dim3(8, 64), 256, 0, stream>>>(Ctx, Wob, bo, out, nullptr, nullptr,
                                              8192, 1024, 1024);
}

// Round 4
// 203.641 us; speedup vs baseline: 1.5694x; 1.1366x over previous
//
#include <hip/hip_runtime.h>
#include <hip/hip_bf16.h>
#include <stdint.h>

// Problem constants
#define TLEN 2048
#define NHEAD 16
#define CD 1024
#define HDIM 64

typedef __attribute__((ext_vector_type(4))) float f32x4;
typedef __attribute__((ext_vector_type(8))) short s16x8;
typedef __attribute__((ext_vector_type(8))) unsigned short u16x8;
typedef __attribute__((ext_vector_type(4))) unsigned short u16x4;
typedef __attribute__((ext_vector_type(2))) unsigned int u32x2;

typedef __attribute__((address_space(1))) const unsigned int global_u32;
typedef __attribute__((address_space(3))) unsigned int lds_u32;

__device__ __forceinline__ void gl_lds16(const void* g, void* l) {
  __builtin_amdgcn_global_load_lds((global_u32*)g, (lds_u32*)l, 16, 0, 0);
}

__device__ __forceinline__ unsigned short f2bf(float x) {
  unsigned int u = __float_as_uint(x);
  u += 0x7fffu + ((u >> 16) & 1u);   // RTNE; inputs finite
  return (unsigned short)(u >> 16);
}

__device__ __forceinline__ f32x4 mfma_bf16(s16x8 a, s16x8 b, f32x4 c) {
  return __builtin_amdgcn_mfma_f32_16x16x32_bf16(a, b, c, 0, 0, 0);
}

// ---------------- fp32 -> bf16 cast, 8 elems/thread ----------------
__global__ __launch_bounds__(256) void cvt_bf16(const float* __restrict__ src,
                                                unsigned short* __restrict__ dst) {
  int i = (blockIdx.x * 256 + threadIdx.x) * 8;
  float4 a = *(const float4*)(src + i);
  float4 b = *(const float4*)(src + i + 4);
  u16x8 o;
  o[0] = f2bf(a.x); o[1] = f2bf(a.y); o[2] = f2bf(a.z); o[3] = f2bf(a.w);
  o[4] = f2bf(b.x); o[5] = f2bf(b.y); o[6] = f2bf(b.z); o[7] = f2bf(b.w);
  *(u16x8*)(dst + i) = o;
}

// ---------------- GEMM: C[M][N] = A[M][K] * Bw[N][K]^T + bias ----------------
#define BM 128
#define BN 128
#define BKG 64

template <int SPLIT>
__global__ __launch_bounds__(256) void gemm_bt(
    const unsigned short* __restrict__ A, const unsigned short* __restrict__ Bw,
    const float* __restrict__ bias, float* __restrict__ Cf,
    unsigned short* __restrict__ qk_out, unsigned short* __restrict__ vt_out,
    int M, int N, int K) {
  __shared__ char lds[(BM + BN) * BKG * 2];   // 32 KiB
  char* aL = lds;
  char* bL = lds + BM * BKG * 2;
  const int tid = threadIdx.x;
  const int w = tid >> 6, l = tid & 63, l15 = l & 15, l4 = l >> 4;
  const int wr = w >> 1, wc = w & 1;

  // T1: XCD-aware flat swizzle (nwg % 8 == 0 for both launches)
  const int nbx = gridDim.x;
  const int nwg = nbx * gridDim.y;
  int f = blockIdx.y * nbx + blockIdx.x;
  f = (f & 7) * (nwg >> 3) + (f >> 3);
  const int brow = (f / nbx) * BM, bcol = (f % nbx) * BN;

  f32x4 z4 = {0.f, 0.f, 0.f, 0.f};
  f32x4 acc[4][4];
#pragma unroll
  for (int m = 0; m < 4; ++m)
#pragma unroll
    for (int n = 0; n < 4; ++n) acc[m][n] = z4;

  const unsigned short* Ab = A + (size_t)brow * K;
  const unsigned short* Bb = Bw + (size_t)bcol * K;

  for (int k0 = 0; k0 < K; k0 += BKG) {
    __syncthreads();
#pragma unroll
    for (int i = 0; i < 4; ++i) {
      int ch = i * 256 + tid;
      int r = ch >> 3, c = ch & 7;
      int cs = (c ^ (r & 7)) * 8;
      gl_lds16(Ab + (size_t)r * K + k0 + cs, aL + ch * 16);
      gl_lds16(Bb + (size_t)r * K + k0 + cs, bL + ch * 16);
    }
    __syncthreads();
#pragma unroll
    for (int kk = 0; kk < 2; ++kk) {
      s16x8 af[4], bfr[4];
#pragma unroll
      for (int m = 0; m < 4; ++m) {
        int r = wr * 64 + m * 16 + l15;
        af[m] = *(const s16x8*)(aL + r * (BKG * 2) +
                                ((kk * 64 + l4 * 16) ^ ((r & 7) << 4)));
      }
#pragma unroll
      for (int n = 0; n < 4; ++n) {
        int r = wc * 64 + n * 16 + l15;
        bfr[n] = *(const s16x8*)(bL + r * (BKG * 2) +
                                 ((kk * 64 + l4 * 16) ^ ((r & 7) << 4)));
      }
#pragma unroll
      for (int m = 0; m < 4; ++m)
#pragma unroll
        for (int n = 0; n < 4; ++n) acc[m][n] = mfma_bf16(af[m], bfr[n], acc[m][n]);
    }
  }

#pragma unroll
  for (int m = 0; m < 4; ++m) {
    int row0 = brow + wr * 64 + m * 16 + l4 * 4;
#pragma unroll
    for (int n = 0; n < 4; ++n) {
      int col = bcol + wc * 64 + n * 16 + l15;
      float bs = bias[col];
      if (SPLIT == 0) {
#pragma unroll
        for (int r = 0; r < 4; ++r)
          Cf[(size_t)(row0 + r) * N + col] = acc[m][n][r] + bs;
      } else {
        if (col < 2 * CD) {
#pragma unroll
          for (int r = 0; r < 4; ++r)
            qk_out[(size_t)(row0 + r) * (2 * CD) + col] = f2bf(acc[m][n][r] + bs);
        } else {
          int cc = col - 2 * CD;
          int b_ = row0 >> 11;
          int t = row0 & (TLEN - 1);
          u16x4 pk;
#pragma unroll
          for (int r = 0; r < 4; ++r) pk[r] = f2bf(acc[m][n][r] + bs);
          *(u16x4*)(vt_out + (size_t)(b_ * CD + cc) * TLEN + t) = pk;
        }
      }
    }
  }
}

// ---------------- flash attention (swapped QK^T, paired q-tiles) -------------
// grid 1024 blocks; decode maps 16 pair-slots of 8 bh onto each XCD so the
// XCD's L2 (4 MiB) holds those heads' K/V (8 x 512 KB). Block with slot jp
// handles q-tiles jp and 31-jp: uniform 33 tile-iters. K/V double-buffered,
// raw s_barrier + counted vmcnt (T3/T4 minimum form).
// Swapped S^T = mfma(K,Q): lane owns q=l&15, 16 kv values in-register.
// Cross-lane (row max across l4 groups, corr broadcast to accumulator rows)
// goes through wave-private LDS scratch (in-order DS pipe; no wide shfl).
__global__ __launch_bounds__(256) void attn_fwd(
    const unsigned short* __restrict__ qk,   // [B*T][2048] bf16: Q | K
    const unsigned short* __restrict__ vt,   // [B*H*64][2048] = V^T per head
    unsigned short* __restrict__ ctx) {      // [B*T][1024]
  __shared__ char k_lds[2 * 64 * 128];      // K tiles [kv][d], swizzled
  __shared__ char v_lds[2 * 64 * 128];      // V^T tiles [d][kv], swizzled
  __shared__ char p_lds[4 * 16 * 128];      // per-wave P [16 q][64 kv], swizzled

  const int fblk = blockIdx.y * 16 + blockIdx.x;
  const int xcd = fblk & 7, g = fblk >> 3;
  const int bh = xcd * 8 + (g & 7);          // 8 bh per XCD
  const int jp = g >> 3;                     // 0..15 pair-slot
  const int b = bh >> 4, h = bh & 15;
  const int tid = threadIdx.x;
  const int w = tid >> 6, l = tid & 63, l15 = l & 15, l4 = l >> 4;

  const unsigned short* Kg = qk + (size_t)b * TLEN * (2 * CD) + CD + h * HDIM;
  const unsigned short* Vg = vt + (size_t)bh * HDIM * TLEN;

  const float SC2 = 0.18033688011112042f;   // (1/sqrt(64)) * log2(e)
  char* pw = p_lds + w * 2048;              // wave-private 16x128B region

  s16x8 onesf;                              // bf16 1.0 broadcast B-fragment
#pragma unroll
  for (int j = 0; j < 8; ++j) onesf[j] = (short)0x3F80;

  f32x4 z4 = {0.f, 0.f, 0.f, 0.f};

  for (int seg = 0; seg < 2; ++seg) {
    const int qi = seg == 0 ? jp : 31 - jp;
    const int nt = qi + 1;

    // Q fragments (B-operand): col q = l15, k: d = l4*8 + j
    const unsigned short* qrow =
        qk + (size_t)(b * TLEN + qi * 64 + w * 16 + l15) * (2 * CD) + h * HDIM;
    s16x8 qf0 = *(const s16x8*)(qrow + l4 * 8);
    s16x8 qf1 = *(const s16x8*)(qrow + 32 + l4 * 8);

    f32x4 acc_o[4];
#pragma unroll
    for (int dc = 0; dc < 4; ++dc) acc_o[dc] = z4;
    f32x4 acc_l = z4;                       // softmax denominator (ones-MFMA)
    float m_r = -3.0e38f;                   // running max for q = l15

    auto stage = [&](int buf, int kt) {
#pragma unroll
      for (int i = 0; i < 2; ++i) {
        int ch = i * 256 + tid;
        int r = ch >> 3, c = ch & 7;
        int cs = (c ^ (r & 7)) * 8;
        gl_lds16(Kg + (size_t)(kt * 64 + r) * (2 * CD) + cs,
                 k_lds + buf * 8192 + ch * 16);
        gl_lds16(Vg + (size_t)r * TLEN + kt * 64 + cs,
                 v_lds + buf * 8192 + ch * 16);
      }
    };

    __builtin_amdgcn_s_barrier();           // seg boundary: both bufs free
    stage(0, 0);
    int cur = 0;

    for (int kt = 0; kt < nt; ++kt) {
      __builtin_amdgcn_s_barrier();         // all waves done reading buf^1
      if (kt + 1 < nt) {
        stage(cur ^ 1, kt + 1);
        asm volatile("s_waitcnt vmcnt(4)" ::: "memory");  // cur's 4 loads done
      } else {
        asm volatile("s_waitcnt vmcnt(0)" ::: "memory");
      }
      __builtin_amdgcn_sched_barrier(0);
      __builtin_amdgcn_s_barrier();         // buf[cur] visible to all waves
      __builtin_amdgcn_sched_barrier(0);

      const char* kb = k_lds + cur * 8192;
      const char* vb = v_lds + cur * 8192;

      // S^T = K Q^T : A = K (m = kv), B = Q (n = q). Lane: q = l15,
      // kv = n*16 + l4*4 + r.
      f32x4 s[4];
#pragma unroll
      for (int n = 0; n < 4; ++n) {
        int r = n * 16 + l15;
        int sw = (r & 7) << 4;
        s16x8 kf0 = *(const s16x8*)(kb + r * 128 + ((l4 * 16) ^ sw));
        s16x8 kf1 = *(const s16x8*)(kb + r * 128 + ((64 + l4 * 16) ^ sw));
        f32x4 z = z4;
        z = mfma_bf16(kf0, qf0, z);
        z = mfma_bf16(kf1, qf1, z);
        s[n] = z;
      }

      if (kt == qi) {                       // causal mask, diagonal tile only
        int ql = w * 16 + l15;
#pragma unroll
        for (int n = 0; n < 4; ++n)
#pragma unroll
          for (int r = 0; r < 4; ++r)
            if ((n * 16 + l4 * 4 + r) > ql) s[n][r] = -3.0e38f;
      }

      // in-lane partial max over this lane's 16 kv values
      float t0 = fmaxf(fmaxf(s[0][0], s[0][1]), fmaxf(s[0][2], s[0][3]));
      float t1 = fmaxf(fmaxf(s[1][0], s[1][1]), fmaxf(s[1][2], s[1][3]));
      float t2 = fmaxf(fmaxf(s[2][0], s[2][1]), fmaxf(s[2][2], s[2][3]));
      float t3 = fmaxf(fmaxf(s[3][0], s[3][1]), fmaxf(s[3][2], s[3][3]));
      float tm = fmaxf(fmaxf(t0, t1), fmaxf(t2, t3));

      // cross-lane max across the 4 l4-groups via wave-private LDS scratch
      // (bytes 0..255 of pw; overwritten by P below, after corr4 is read)
      *(float*)(pw + l * 4) = tm;
      asm volatile("s_waitcnt lgkmcnt(0)" ::: "memory");
      __builtin_amdgcn_sched_barrier(0);
      float m0 = *(const float*)(pw + l15 * 4);
      float m1 = *(const float*)(pw + (l15 + 16) * 4);
      float m2 = *(const float*)(pw + (l15 + 32) * 4);
      float m3 = *(const float*)(pw + (l15 + 48) * 4);
      float tmax = fmaxf(fmaxf(m0, m1), fmaxf(m2, m3));

      float m_n = fmaxf(m_r, tmax);
      float corr = __builtin_amdgcn_exp2f((m_r - m_n) * SC2);
      m_r = m_n;

      // broadcast corr (per q-row l15, uniform across l4 group) to the
      // accumulator-row layout q = l4*4 + r, via LDS (4 same-value writers)
      *(float*)(pw + 256 + l15 * 4) = corr;
      asm volatile("s_waitcnt lgkmcnt(0)" ::: "memory");
      __builtin_amdgcn_sched_barrier(0);
      float corr4[4];
#pragma unroll
      for (int r = 0; r < 4; ++r)
        corr4[r] = *(const float*)(pw + 256 + (l4 * 4 + r) * 4);

      // P = exp2(s*SC2 - m*SC2) -> bf16 pairs -> b64 writes, row q = l15
      float msc = m_n * SC2;
#pragma unroll
      for (int n = 0; n < 4; ++n) {
        float p0 = __builtin_amdgcn_exp2f(fmaf(s[n][0], SC2, -msc));
        float p1 = __builtin_amdgcn_exp2f(fmaf(s[n][1], SC2, -msc));
        float p2 = __builtin_amdgcn_exp2f(fmaf(s[n][2], SC2, -msc));
        float p3 = __builtin_amdgcn_exp2f(fmaf(s[n][3], SC2, -msc));
        unsigned int lo = (unsigned int)f2bf(p0) | ((unsigned int)f2bf(p1) << 16);
        unsigned int hi = (unsigned int)f2bf(p2) | ((unsigned int)f2bf(p3) << 16);
        u32x2 pr; pr[0] = lo; pr[1] = hi;
        *(u32x2*)(pw + l15 * 128 + ((n * 32 + l4 * 8) ^ ((l15 & 7) << 4))) = pr;
      }

      // rescale running accumulators (rows q = l4*4 + r)
#pragma unroll
      for (int r = 0; r < 4; ++r) {
        acc_l[r] *= corr4[r];
#pragma unroll
        for (int dc = 0; dc < 4; ++dc) acc_o[dc][r] *= corr4[r];
      }

      // P writes are wave-private; DS pipe is in-order per wave, just drain
      asm volatile("s_waitcnt lgkmcnt(0)" ::: "memory");
      __builtin_amdgcn_sched_barrier(0);

      // O += P V ; denominator += P * ones
#pragma unroll
      for (int kc = 0; kc < 2; ++kc) {
        s16x8 pf = *(const s16x8*)(pw + l15 * 128 +
                                   ((kc * 64 + l4 * 16) ^ ((l15 & 7) << 4)));
        acc_l = mfma_bf16(pf, onesf, acc_l);
#pragma unroll
        for (int dc = 0; dc < 4; ++dc) {
          int rd = dc * 16 + l15;
          s16x8 vf = *(const s16x8*)(vb + rd * 128 +
                                     ((kc * 64 + l4 * 16) ^ ((rd & 7) << 4)));
          acc_o[dc] = mfma_bf16(pf, vf, acc_o[dc]);
        }
      }
      cur ^= 1;
    }

    // normalize + write ctx (bf16)
#pragma unroll
    for (int r = 0; r < 4; ++r) {
      int qg = qi * 64 + w * 16 + l4 * 4 + r;
      float inv = 1.0f / acc_l[r];
      size_t base = (size_t)(b * TLEN + qg) * CD + h * HDIM;
#pragma unroll
      for (int dc = 0; dc < 4; ++dc)
        ctx[base + dc * 16 + l15] = f2bf(acc_o[dc][r] * inv);
    }
  }
}

// ---------------- launch ----------------
extern "C" void kernel_launch(void* const* d_in, const int* in_sizes, int n_in,
                              void* d_out, int out_size, void* d_ws, size_t ws_size,
                              hipStream_t stream) {
  const float* X  = (const float*)d_in[0];   // [4,2048,1024]
  const float* Wq = (const float*)d_in[1];   // [3072,1024]
  const float* bq = (const float*)d_in[2];   // [3072]
  const float* Wo = (const float*)d_in[3];   // [1024,1024]
  const float* bo = (const float*)d_in[4];   // [1024]
  float* out = (float*)d_out;

  char* ws = (char*)d_ws;
  unsigned short* Xb  = (unsigned short*)ws;                       // 16.78 MB
  unsigned short* Wqb = (unsigned short*)(ws + 16777216);          //  6.29 MB
  unsigned short* Wob = (unsigned short*)(ws + 23068672);          //  2.10 MB
  unsigned short* QK  = (unsigned short*)(ws + 25165824);          // 33.55 MB
  unsigned short* Vt  = (unsigned short*)(ws + 58720256);          // 16.78 MB
  unsigned short* Ctx = Xb;   // alias: Xb dead after QKV GEMM     // total 75.5 MB

  cvt_bf16<<<4096, 256, 0, stream>>>(X, Xb);
  cvt_bf16<<<1536, 256, 0, stream>>>(Wq, Wqb);
  cvt_bf16<<<512, 256, 0, stream>>>(Wo, Wob);

  gemm_bt<1><<<dim3(24, 64), 256, 0, stream>>>(Xb, Wqb, bq, nullptr, QK, Vt,
                                               8192, 3072, 1024);
  attn_fwd<<<dim3(16, 64), 256, 0, stream>>>(QK, Vt, Ctx);
  gemm_bt<0><<<dim3(8, 64), 256, 0, stream>>>(Ctx, Wob, bo, out, nullptr, nullptr,
                                              8192, 1024, 1024);
}

// Round 5
// 200.440 us; speedup vs baseline: 1.5945x; 1.0160x over previous
//
#include <hip/hip_runtime.h>
#include <hip/hip_bf16.h>
#include <stdint.h>

// Problem constants
#define TLEN 2048
#define NHEAD 16
#define CD 1024
#define HDIM 64

typedef __attribute__((ext_vector_type(4))) float f32x4;
typedef __attribute__((ext_vector_type(8))) short s16x8;
typedef __attribute__((ext_vector_type(8))) unsigned short u16x8;
typedef __attribute__((ext_vector_type(4))) unsigned short u16x4;
typedef __attribute__((ext_vector_type(2))) unsigned int u32x2;

typedef __attribute__((address_space(1))) const unsigned int global_u32;
typedef __attribute__((address_space(3))) unsigned int lds_u32;

__device__ __forceinline__ void gl_lds16(const void* g, void* l) {
  __builtin_amdgcn_global_load_lds((global_u32*)g, (lds_u32*)l, 16, 0, 0);
}

__device__ __forceinline__ unsigned short f2bf(float x) {
  unsigned int u = __float_as_uint(x);
  u += 0x7fffu + ((u >> 16) & 1u);   // RTNE; inputs finite
  return (unsigned short)(u >> 16);
}

__device__ __forceinline__ f32x4 mfma_bf16(s16x8 a, s16x8 b, f32x4 c) {
  return __builtin_amdgcn_mfma_f32_16x16x32_bf16(a, b, c, 0, 0, 0);
}

// ---------------- fp32 -> bf16 cast, 8 elems/thread ----------------
__global__ __launch_bounds__(256) void cvt_bf16(const float* __restrict__ src,
                                                unsigned short* __restrict__ dst) {
  int i = (blockIdx.x * 256 + threadIdx.x) * 8;
  float4 a = *(const float4*)(src + i);
  float4 b = *(const float4*)(src + i + 4);
  u16x8 o;
  o[0] = f2bf(a.x); o[1] = f2bf(a.y); o[2] = f2bf(a.z); o[3] = f2bf(a.w);
  o[4] = f2bf(b.x); o[5] = f2bf(b.y); o[6] = f2bf(b.z); o[7] = f2bf(b.w);
  *(u16x8*)(dst + i) = o;
}

// ---------------- GEMM: C[M][N] = A[M][K] * Bw[N][K]^T + bias ----------------
#define BM 128
#define BN 128
#define BKG 64

template <int SPLIT>
__global__ __launch_bounds__(256) void gemm_bt(
    const unsigned short* __restrict__ A, const unsigned short* __restrict__ Bw,
    const float* __restrict__ bias, float* __restrict__ Cf,
    unsigned short* __restrict__ qk_out, unsigned short* __restrict__ vt_out,
    int M, int N, int K) {
  __shared__ char lds[(BM + BN) * BKG * 2];   // 32 KiB
  char* aL = lds;
  char* bL = lds + BM * BKG * 2;
  const int tid = threadIdx.x;
  const int w = tid >> 6, l = tid & 63, l15 = l & 15, l4 = l >> 4;
  const int wr = w >> 1, wc = w & 1;

  // T1: XCD-aware flat swizzle (nwg % 8 == 0 for both launches)
  const int nbx = gridDim.x;
  const int nwg = nbx * gridDim.y;
  int f = blockIdx.y * nbx + blockIdx.x;
  f = (f & 7) * (nwg >> 3) + (f >> 3);
  const int brow = (f / nbx) * BM, bcol = (f % nbx) * BN;

  f32x4 z4 = {0.f, 0.f, 0.f, 0.f};
  f32x4 acc[4][4];
#pragma unroll
  for (int m = 0; m < 4; ++m)
#pragma unroll
    for (int n = 0; n < 4; ++n) acc[m][n] = z4;

  const unsigned short* Ab = A + (size_t)brow * K;
  const unsigned short* Bb = Bw + (size_t)bcol * K;

  for (int k0 = 0; k0 < K; k0 += BKG) {
    __syncthreads();
#pragma unroll
    for (int i = 0; i < 4; ++i) {
      int ch = i * 256 + tid;
      int r = ch >> 3, c = ch & 7;
      int cs = (c ^ (r & 7)) * 8;
      gl_lds16(Ab + (size_t)r * K + k0 + cs, aL + ch * 16);
      gl_lds16(Bb + (size_t)r * K + k0 + cs, bL + ch * 16);
    }
    __syncthreads();
#pragma unroll
    for (int kk = 0; kk < 2; ++kk) {
      s16x8 af[4], bfr[4];
#pragma unroll
      for (int m = 0; m < 4; ++m) {
        int r = wr * 64 + m * 16 + l15;
        af[m] = *(const s16x8*)(aL + r * (BKG * 2) +
                                ((kk * 64 + l4 * 16) ^ ((r & 7) << 4)));
      }
#pragma unroll
      for (int n = 0; n < 4; ++n) {
        int r = wc * 64 + n * 16 + l15;
        bfr[n] = *(const s16x8*)(bL + r * (BKG * 2) +
                                 ((kk * 64 + l4 * 16) ^ ((r & 7) << 4)));
      }
#pragma unroll
      for (int m = 0; m < 4; ++m)
#pragma unroll
        for (int n = 0; n < 4; ++n) acc[m][n] = mfma_bf16(af[m], bfr[n], acc[m][n]);
    }
  }

#pragma unroll
  for (int m = 0; m < 4; ++m) {
    int row0 = brow + wr * 64 + m * 16 + l4 * 4;
#pragma unroll
    for (int n = 0; n < 4; ++n) {
      int col = bcol + wc * 64 + n * 16 + l15;
      float bs = bias[col];
      if (SPLIT == 0) {
#pragma unroll
        for (int r = 0; r < 4; ++r)
          Cf[(size_t)(row0 + r) * N + col] = acc[m][n][r] + bs;
      } else {
        if (col < 2 * CD) {
#pragma unroll
          for (int r = 0; r < 4; ++r)
            qk_out[(size_t)(row0 + r) * (2 * CD) + col] = f2bf(acc[m][n][r] + bs);
        } else {
          int cc = col - 2 * CD;
          int b_ = row0 >> 11;
          int t = row0 & (TLEN - 1);
          u16x4 pk;
#pragma unroll
          for (int r = 0; r < 4; ++r) pk[r] = f2bf(acc[m][n][r] + bs);
          *(u16x4*)(vt_out + (size_t)(b_ * CD + cc) * TLEN + t) = pk;
        }
      }
    }
  }
}

// ---------------- flash attention (swapped QK^T, paired q-tiles) -------------
// grid 1024 blocks; decode maps 16 pair-slots of 8 bh onto each XCD so the
// XCD's L2 (4 MiB) holds those heads' K/V (8 x 512 KB). Block with slot jp
// handles q-tiles jp and 31-jp: uniform 33 tile-iters. K/V double-buffered,
// raw s_barrier + counted vmcnt (T3/T4 minimum form).
// Swapped S^T = mfma(K,Q): lane owns q=l&15, 16 kv values in-register.
// Cross-lane via wave-private LDS scratch. Defer-max (T13, THR=8): most
// tiles skip the rescale + corr broadcast. P packed by truncation.
__global__ __launch_bounds__(256) void attn_fwd(
    const unsigned short* __restrict__ qk,   // [B*T][2048] bf16: Q | K
    const unsigned short* __restrict__ vt,   // [B*H*64][2048] = V^T per head
    unsigned short* __restrict__ ctx) {      // [B*T][1024]
  __shared__ char k_lds[2 * 64 * 128];      // K tiles [kv][d], swizzled
  __shared__ char v_lds[2 * 64 * 128];      // V^T tiles [d][kv], swizzled
  __shared__ char p_lds[4 * 16 * 128];      // per-wave P [16 q][64 kv], swizzled

  const int fblk = blockIdx.y * 16 + blockIdx.x;
  const int xcd = fblk & 7, g = fblk >> 3;
  const int bh = xcd * 8 + (g & 7);          // 8 bh per XCD
  const int jp = g >> 3;                     // 0..15 pair-slot
  const int b = bh >> 4, h = bh & 15;
  const int tid = threadIdx.x;
  const int w = tid >> 6, l = tid & 63, l15 = l & 15, l4 = l >> 4;

  const unsigned short* Kg = qk + (size_t)b * TLEN * (2 * CD) + CD + h * HDIM;
  const unsigned short* Vg = vt + (size_t)bh * HDIM * TLEN;

  const float SC2 = 0.18033688011112042f;   // (1/sqrt(64)) * log2(e)
  char* pw = p_lds + w * 2048;              // wave-private 16x128B region

  s16x8 onesf;                              // bf16 1.0 broadcast B-fragment
#pragma unroll
  for (int j = 0; j < 8; ++j) onesf[j] = (short)0x3F80;

  f32x4 z4 = {0.f, 0.f, 0.f, 0.f};

  for (int seg = 0; seg < 2; ++seg) {
    const int qi = seg == 0 ? jp : 31 - jp;
    const int nt = qi + 1;

    // Q fragments (B-operand): col q = l15, k: d = l4*8 + j
    const unsigned short* qrow =
        qk + (size_t)(b * TLEN + qi * 64 + w * 16 + l15) * (2 * CD) + h * HDIM;
    s16x8 qf0 = *(const s16x8*)(qrow + l4 * 8);
    s16x8 qf1 = *(const s16x8*)(qrow + 32 + l4 * 8);

    f32x4 acc_o[4];
#pragma unroll
    for (int dc = 0; dc < 4; ++dc) acc_o[dc] = z4;
    f32x4 acc_l = z4;                       // softmax denominator (ones-MFMA)
    float m_r = -3.0e38f;                   // running max for q = l15

    auto stage = [&](int buf, int kt) {
#pragma unroll
      for (int i = 0; i < 2; ++i) {
        int ch = i * 256 + tid;
        int r = ch >> 3, c = ch & 7;
        int cs = (c ^ (r & 7)) * 8;
        gl_lds16(Kg + (size_t)(kt * 64 + r) * (2 * CD) + cs,
                 k_lds + buf * 8192 + ch * 16);
        gl_lds16(Vg + (size_t)r * TLEN + kt * 64 + cs,
                 v_lds + buf * 8192 + ch * 16);
      }
    };

    __builtin_amdgcn_s_barrier();           // seg boundary: both bufs free
    stage(0, 0);
    int cur = 0;

    for (int kt = 0; kt < nt; ++kt) {
      __builtin_amdgcn_s_barrier();         // all waves done reading buf^1
      if (kt + 1 < nt) {
        stage(cur ^ 1, kt + 1);
        asm volatile("s_waitcnt vmcnt(4)" ::: "memory");  // cur's 4 loads done
      } else {
        asm volatile("s_waitcnt vmcnt(0)" ::: "memory");
      }
      __builtin_amdgcn_sched_barrier(0);
      __builtin_amdgcn_s_barrier();         // buf[cur] visible to all waves
      __builtin_amdgcn_sched_barrier(0);

      const char* kb = k_lds + cur * 8192;
      const char* vb = v_lds + cur * 8192;

      // S^T = K Q^T : A = K (m = kv), B = Q (n = q). Lane: q = l15,
      // kv = n*16 + l4*4 + r.
      f32x4 s[4];
      __builtin_amdgcn_s_setprio(1);
#pragma unroll
      for (int n = 0; n < 4; ++n) {
        int r = n * 16 + l15;
        int sw = (r & 7) << 4;
        s16x8 kf0 = *(const s16x8*)(kb + r * 128 + ((l4 * 16) ^ sw));
        s16x8 kf1 = *(const s16x8*)(kb + r * 128 + ((64 + l4 * 16) ^ sw));
        f32x4 z = z4;
        z = mfma_bf16(kf0, qf0, z);
        z = mfma_bf16(kf1, qf1, z);
        s[n] = z;
      }
      __builtin_amdgcn_s_setprio(0);

      if (kt == qi) {                       // causal mask, diagonal tile only
        int ql = w * 16 + l15;
#pragma unroll
        for (int n = 0; n < 4; ++n)
#pragma unroll
          for (int r = 0; r < 4; ++r)
            if ((n * 16 + l4 * 4 + r) > ql) s[n][r] = -3.0e38f;
      }

      // in-lane partial max over this lane's 16 kv values
      float t0 = fmaxf(fmaxf(s[0][0], s[0][1]), fmaxf(s[0][2], s[0][3]));
      float t1 = fmaxf(fmaxf(s[1][0], s[1][1]), fmaxf(s[1][2], s[1][3]));
      float t2 = fmaxf(fmaxf(s[2][0], s[2][1]), fmaxf(s[2][2], s[2][3]));
      float t3 = fmaxf(fmaxf(s[3][0], s[3][1]), fmaxf(s[3][2], s[3][3]));
      float tm = fmaxf(fmaxf(t0, t1), fmaxf(t2, t3));

      // cross-lane max across the 4 l4-groups via wave-private LDS scratch
      *(float*)(pw + l * 4) = tm;
      asm volatile("s_waitcnt lgkmcnt(0)" ::: "memory");
      __builtin_amdgcn_sched_barrier(0);
      float m0 = *(const float*)(pw + l15 * 4);
      float m1 = *(const float*)(pw + (l15 + 16) * 4);
      float m2 = *(const float*)(pw + (l15 + 32) * 4);
      float m3 = *(const float*)(pw + (l15 + 48) * 4);
      float tmax = fmaxf(fmaxf(m0, m1), fmaxf(m2, m3));

      // defer-max (T13): only rescale when the max grew by more than THR
      if (!__all((tmax - m_r) * SC2 <= 8.0f)) {
        float m_n = fmaxf(m_r, tmax);
        float corr = __builtin_amdgcn_exp2f((m_r - m_n) * SC2);
        m_r = m_n;
        // broadcast corr (per q-row l15) to accumulator layout q = l4*4+r
        *(float*)(pw + 256 + l15 * 4) = corr;
        asm volatile("s_waitcnt lgkmcnt(0)" ::: "memory");
        __builtin_amdgcn_sched_barrier(0);
        float corr4[4];
#pragma unroll
        for (int r = 0; r < 4; ++r)
          corr4[r] = *(const float*)(pw + 256 + (l4 * 4 + r) * 4);
#pragma unroll
        for (int r = 0; r < 4; ++r) {
          acc_l[r] *= corr4[r];
#pragma unroll
          for (int dc = 0; dc < 4; ++dc) acc_o[dc][r] *= corr4[r];
        }
      }

      // P = exp2(s*SC2 - m*SC2), bounded by 2^8 -> truncation pack -> b64
      float msc = m_r * SC2;
#pragma unroll
      for (int n = 0; n < 4; ++n) {
        float p0 = __builtin_amdgcn_exp2f(fmaf(s[n][0], SC2, -msc));
        float p1 = __builtin_amdgcn_exp2f(fmaf(s[n][1], SC2, -msc));
        float p2 = __builtin_amdgcn_exp2f(fmaf(s[n][2], SC2, -msc));
        float p3 = __builtin_amdgcn_exp2f(fmaf(s[n][3], SC2, -msc));
        unsigned int lo = (__float_as_uint(p1) & 0xffff0000u) |
                          (__float_as_uint(p0) >> 16);
        unsigned int hi = (__float_as_uint(p3) & 0xffff0000u) |
                          (__float_as_uint(p2) >> 16);
        u32x2 pr; pr[0] = lo; pr[1] = hi;
        *(u32x2*)(pw + l15 * 128 + ((n * 32 + l4 * 8) ^ ((l15 & 7) << 4))) = pr;
      }

      // P writes are wave-private; DS pipe is in-order per wave, just drain
      asm volatile("s_waitcnt lgkmcnt(0)" ::: "memory");
      __builtin_amdgcn_sched_barrier(0);

      // O += P V ; denominator += P * ones
      __builtin_amdgcn_s_setprio(1);
#pragma unroll
      for (int kc = 0; kc < 2; ++kc) {
        s16x8 pf = *(const s16x8*)(pw + l15 * 128 +
                                   ((kc * 64 + l4 * 16) ^ ((l15 & 7) << 4)));
        acc_l = mfma_bf16(pf, onesf, acc_l);
#pragma unroll
        for (int dc = 0; dc < 4; ++dc) {
          int rd = dc * 16 + l15;
          s16x8 vf = *(const s16x8*)(vb + rd * 128 +
                                     ((kc * 64 + l4 * 16) ^ ((rd & 7) << 4)));
          acc_o[dc] = mfma_bf16(pf, vf, acc_o[dc]);
        }
      }
      __builtin_amdgcn_s_setprio(0);
      cur ^= 1;
    }

    // normalize + write ctx (bf16)
#pragma unroll
    for (int r = 0; r < 4; ++r) {
      int qg = qi * 64 + w * 16 + l4 * 4 + r;
      float inv = 1.0f / acc_l[r];
      size_t base = (size_t)(b * TLEN + qg) * CD + h * HDIM;
#pragma unroll
      for (int dc = 0; dc < 4; ++dc)
        ctx[base + dc * 16 + l15] = f2bf(acc_o[dc][r] * inv);
    }
  }
}

// ---------------- launch ----------------
extern "C" void kernel_launch(void* const* d_in, const int* in_sizes, int n_in,
                              void* d_out, int out_size, void* d_ws, size_t ws_size,
                              hipStream_t stream) {
  const float* X  = (const float*)d_in[0];   // [4,2048,1024]
  const float* Wq = (const float*)d_in[1];   // [3072,1024]
  const float* bq = (const float*)d_in[2];   // [3072]
  const float* Wo = (const float*)d_in[3];   // [1024,1024]
  const float* bo = (const float*)d_in[4];   // [1024]
  float* out = (float*)d_out;

  char* ws = (char*)d_ws;
  unsigned short* Xb  = (unsigned short*)ws;                       // 16.78 MB
  unsigned short* Wqb = (unsigned short*)(ws + 16777216);          //  6.29 MB
  unsigned short* Wob = (unsigned short*)(ws + 23068672);          //  2.10 MB
  unsigned short* QK  = (unsigned short*)(ws + 25165824);          // 33.55 MB
  unsigned short* Vt  = (unsigned short*)(ws + 58720256);          // 16.78 MB
  unsigned short* Ctx = Xb;   // alias: Xb dead after QKV GEMM     // total 75.5 MB

  cvt_bf16<<<4096, 256, 0, stream>>>(X, Xb);
  cvt_bf16<<<1536, 256, 0, stream>>>(Wq, Wqb);
  cvt_bf16<<<512, 256, 0, stream>>>(Wo, Wob);

  gemm_bt<1><<<dim3(24, 64), 256, 0, stream>>>(Xb, Wqb, bq, nullptr, QK, Vt,
                                               8192, 3072, 1024);
  attn_fwd<<<dim3(16, 64), 256, 0, stream>>>(QK, Vt, Ctx);
  gemm_bt<0><<<dim3(8, 64), 256, 0, stream>>>(Ctx, Wob, bo, out, nullptr, nullptr,
                                              8192, 1024, 1024);
}

// Round 6
// 199.565 us; speedup vs baseline: 1.6014x; 1.0044x over previous
//
#include <hip/hip_runtime.h>
#include <hip/hip_bf16.h>
#include <stdint.h>

// Problem constants
#define TLEN 2048
#define NHEAD 16
#define CD 1024
#define HDIM 64

typedef __attribute__((ext_vector_type(4))) float f32x4;
typedef __attribute__((ext_vector_type(8))) short s16x8;
typedef __attribute__((ext_vector_type(8))) unsigned short u16x8;
typedef __attribute__((ext_vector_type(4))) unsigned short u16x4;
typedef __attribute__((ext_vector_type(2))) unsigned int u32x2;

typedef __attribute__((address_space(1))) const unsigned int global_u32;
typedef __attribute__((address_space(3))) unsigned int lds_u32;

__device__ __forceinline__ void gl_lds16(const void* g, void* l) {
  __builtin_amdgcn_global_load_lds((global_u32*)g, (lds_u32*)l, 16, 0, 0);
}

__device__ __forceinline__ unsigned short f2bf(float x) {
  unsigned int u = __float_as_uint(x);
  u += 0x7fffu + ((u >> 16) & 1u);   // RTNE; inputs finite
  return (unsigned short)(u >> 16);
}

__device__ __forceinline__ f32x4 mfma_bf16(s16x8 a, s16x8 b, f32x4 c) {
  return __builtin_amdgcn_mfma_f32_16x16x32_bf16(a, b, c, 0, 0, 0);
}

// ---------------- fp32 -> bf16 cast, 8 elems/thread ----------------
__global__ __launch_bounds__(256) void cvt_bf16(const float* __restrict__ src,
                                                unsigned short* __restrict__ dst) {
  int i = (blockIdx.x * 256 + threadIdx.x) * 8;
  float4 a = *(const float4*)(src + i);
  float4 b = *(const float4*)(src + i + 4);
  u16x8 o;
  o[0] = f2bf(a.x); o[1] = f2bf(a.y); o[2] = f2bf(a.z); o[3] = f2bf(a.w);
  o[4] = f2bf(b.x); o[5] = f2bf(b.y); o[6] = f2bf(b.z); o[7] = f2bf(b.w);
  *(u16x8*)(dst + i) = o;
}

// ---------------- GEMM: C[M][N] = A[M][K] * Bw[N][K]^T + bias ----------------
#define BM 128
#define BN 128
#define BKG 64

template <int SPLIT>
__global__ __launch_bounds__(256) void gemm_bt(
    const unsigned short* __restrict__ A, const unsigned short* __restrict__ Bw,
    const float* __restrict__ bias, float* __restrict__ Cf,
    unsigned short* __restrict__ qk_out, unsigned short* __restrict__ vt_out,
    int M, int N, int K) {
  __shared__ char lds[(BM + BN) * BKG * 2];   // 32 KiB
  char* aL = lds;
  char* bL = lds + BM * BKG * 2;
  const int tid = threadIdx.x;
  const int w = tid >> 6, l = tid & 63, l15 = l & 15, l4 = l >> 4;
  const int wr = w >> 1, wc = w & 1;

  // T1: XCD-aware flat swizzle (nwg % 8 == 0 for both launches)
  const int nbx = gridDim.x;
  const int nwg = nbx * gridDim.y;
  int f = blockIdx.y * nbx + blockIdx.x;
  f = (f & 7) * (nwg >> 3) + (f >> 3);
  const int brow = (f / nbx) * BM, bcol = (f % nbx) * BN;

  f32x4 z4 = {0.f, 0.f, 0.f, 0.f};
  f32x4 acc[4][4];
#pragma unroll
  for (int m = 0; m < 4; ++m)
#pragma unroll
    for (int n = 0; n < 4; ++n) acc[m][n] = z4;

  const unsigned short* Ab = A + (size_t)brow * K;
  const unsigned short* Bb = Bw + (size_t)bcol * K;

  for (int k0 = 0; k0 < K; k0 += BKG) {
    __syncthreads();
#pragma unroll
    for (int i = 0; i < 4; ++i) {
      int ch = i * 256 + tid;
      int r = ch >> 3, c = ch & 7;
      int cs = (c ^ (r & 7)) * 8;
      gl_lds16(Ab + (size_t)r * K + k0 + cs, aL + ch * 16);
      gl_lds16(Bb + (size_t)r * K + k0 + cs, bL + ch * 16);
    }
    __syncthreads();
#pragma unroll
    for (int kk = 0; kk < 2; ++kk) {
      s16x8 af[4], bfr[4];
#pragma unroll
      for (int m = 0; m < 4; ++m) {
        int r = wr * 64 + m * 16 + l15;
        af[m] = *(const s16x8*)(aL + r * (BKG * 2) +
                                ((kk * 64 + l4 * 16) ^ ((r & 7) << 4)));
      }
#pragma unroll
      for (int n = 0; n < 4; ++n) {
        int r = wc * 64 + n * 16 + l15;
        bfr[n] = *(const s16x8*)(bL + r * (BKG * 2) +
                                 ((kk * 64 + l4 * 16) ^ ((r & 7) << 4)));
      }
#pragma unroll
      for (int m = 0; m < 4; ++m)
#pragma unroll
        for (int n = 0; n < 4; ++n) acc[m][n] = mfma_bf16(af[m], bfr[n], acc[m][n]);
    }
  }

#pragma unroll
  for (int m = 0; m < 4; ++m) {
    int row0 = brow + wr * 64 + m * 16 + l4 * 4;
#pragma unroll
    for (int n = 0; n < 4; ++n) {
      int col = bcol + wc * 64 + n * 16 + l15;
      float bs = bias[col];
      if (SPLIT == 0) {
#pragma unroll
        for (int r = 0; r < 4; ++r)
          Cf[(size_t)(row0 + r) * N + col] = acc[m][n][r] + bs;
      } else {
        if (col < 2 * CD) {
#pragma unroll
          for (int r = 0; r < 4; ++r)
            qk_out[(size_t)(row0 + r) * (2 * CD) + col] = f2bf(acc[m][n][r] + bs);
        } else {
          int cc = col - 2 * CD;
          int b_ = row0 >> 11;
          int t = row0 & (TLEN - 1);
          u16x4 pk;
#pragma unroll
          for (int r = 0; r < 4; ++r) pk[r] = f2bf(acc[m][n][r] + bs);
          *(u16x4*)(vt_out + (size_t)(b_ * CD + cc) * TLEN + t) = pk;
        }
      }
    }
  }
}

// ---------------- flash attention (swapped QK^T, paired q-tiles) -------------
// grid 1024 blocks; decode maps 16 pair-slots of 8 bh onto each XCD so the
// XCD's L2 holds those heads' K/V. Block with slot jp handles q-tiles jp and
// 31-jp: uniform 33 tile-iters. K/V double-buffered, raw s_barrier + counted
// vmcnt. Swapped S^T = mfma(K,Q): lane owns q=l&15, 16 kv in-register.
// All loop-invariant LDS/global addresses hoisted to registers; row-max via
// shfl_xor(16) + ds_bpermute(lane^32) (no LDS round-trip).
__global__ __launch_bounds__(256) void attn_fwd(
    const unsigned short* __restrict__ qk,   // [B*T][2048] bf16: Q | K
    const unsigned short* __restrict__ vt,   // [B*H*64][2048] = V^T per head
    unsigned short* __restrict__ ctx) {      // [B*T][1024]
  __shared__ char k_lds[2 * 64 * 128];      // K tiles [kv][d], swizzled
  __shared__ char v_lds[2 * 64 * 128];      // V^T tiles [d][kv], swizzled
  __shared__ char p_lds[4 * 16 * 128];      // per-wave P [16 q][64 kv], swizzled

  const int fblk = blockIdx.y * 16 + blockIdx.x;
  const int xcd = fblk & 7, g = fblk >> 3;
  const int bh = xcd * 8 + (g & 7);          // 8 bh per XCD
  const int jp = g >> 3;                     // 0..15 pair-slot
  const int b = bh >> 4, h = bh & 15;
  const int tid = threadIdx.x;
  const int w = tid >> 6, l = tid & 63, l15 = l & 15, l4 = l >> 4;

  const unsigned short* Kg = qk + (size_t)b * TLEN * (2 * CD) + CD + h * HDIM;
  const unsigned short* Vg = vt + (size_t)bh * HDIM * TLEN;

  const float SC2 = 0.18033688011112042f;   // (1/sqrt(64)) * log2(e)
  char* pw = p_lds + w * 2048;              // wave-private 16x128B region

  // ---- loop-invariant address registers ----
  const int sw = (l15 & 7) << 4;
  const int c0 = (l4 * 16) ^ sw;            // kk/kc = 0 column offset
  const int c1 = (64 + l4 * 16) ^ sw;       // kk/kc = 1 column offset
  const int row128 = l15 * 128;
  // P read pointers (block-static LDS)
  const char* prd0 = pw + row128 + c0;
  const char* prd1 = pw + row128 + c1;
  // P write pointers (4, one per n)
  char* pwr0 = pw + row128 + ((0 * 32 + l4 * 8) ^ sw);
  char* pwr1 = pw + row128 + ((1 * 32 + l4 * 8) ^ sw);
  char* pwr2 = pw + row128 + ((2 * 32 + l4 * 8) ^ sw);
  char* pwr3 = pw + row128 + ((3 * 32 + l4 * 8) ^ sw);
  // staging LDS offsets (2 chunks per thread) + swizzled source column
  const int ch0 = tid, ch1 = 256 + tid;
  const int ldsoff0 = ch0 * 16, ldsoff1 = ch1 * 16;
  const int r0 = ch0 >> 3, r1 = ch1 >> 3;
  const int cs0 = ((ch0 & 7) ^ (r0 & 7)) * 8;
  const int cs1 = ((ch1 & 7) ^ (r1 & 7)) * 8;
  const int bperm_addr = (l ^ 32) << 2;     // cross-32 lane for ds_bpermute

  s16x8 onesf;                              // bf16 1.0 broadcast B-fragment
#pragma unroll
  for (int j = 0; j < 8; ++j) onesf[j] = (short)0x3F80;

  f32x4 z4 = {0.f, 0.f, 0.f, 0.f};

  for (int seg = 0; seg < 2; ++seg) {
    const int qi = seg == 0 ? jp : 31 - jp;
    const int nt = qi + 1;

    // Q fragments (B-operand): col q = l15, k: d = l4*8 + j
    const unsigned short* qrow =
        qk + (size_t)(b * TLEN + qi * 64 + w * 16 + l15) * (2 * CD) + h * HDIM;
    s16x8 qf0 = *(const s16x8*)(qrow + l4 * 8);
    s16x8 qf1 = *(const s16x8*)(qrow + 32 + l4 * 8);

    f32x4 acc_o[4];
#pragma unroll
    for (int dc = 0; dc < 4; ++dc) acc_o[dc] = z4;
    f32x4 acc_l = z4;                       // softmax denominator (ones-MFMA)
    float m_r = -3.0e38f;                   // running max for q = l15

    // running global staging pointers (bytes), tile 0
    const char* gk0 = (const char*)Kg + r0 * 4096 + cs0 * 2;
    const char* gk1 = (const char*)Kg + r1 * 4096 + cs1 * 2;
    const char* gv0 = (const char*)Vg + r0 * 4096 + cs0 * 2;
    const char* gv1 = (const char*)Vg + r1 * 4096 + cs1 * 2;

    __builtin_amdgcn_s_barrier();           // seg boundary: both bufs free
    // prologue: stage tile 0 into buf 0
    gl_lds16(gk0, k_lds + ldsoff0);
    gl_lds16(gv0, v_lds + ldsoff0);
    gl_lds16(gk1, k_lds + ldsoff1);
    gl_lds16(gv1, v_lds + ldsoff1);
    gk0 += 262144; gk1 += 262144; gv0 += 128; gv1 += 128;
    int cur = 0;

    for (int kt = 0; kt < nt; ++kt) {
      __builtin_amdgcn_s_barrier();         // all waves done reading buf^1
      if (kt + 1 < nt) {
        int nb = (cur ^ 1) << 13;
        gl_lds16(gk0, k_lds + nb + ldsoff0);
        gl_lds16(gv0, v_lds + nb + ldsoff0);
        gl_lds16(gk1, k_lds + nb + ldsoff1);
        gl_lds16(gv1, v_lds + nb + ldsoff1);
        gk0 += 262144; gk1 += 262144; gv0 += 128; gv1 += 128;
        asm volatile("s_waitcnt vmcnt(4)" ::: "memory");  // cur's 4 loads done
      } else {
        asm volatile("s_waitcnt vmcnt(0)" ::: "memory");
      }
      __builtin_amdgcn_sched_barrier(0);
      __builtin_amdgcn_s_barrier();         // buf[cur] visible to all waves
      __builtin_amdgcn_sched_barrier(0);

      const int cb = cur << 13;
      const char* ka0 = k_lds + cb + row128 + c0;
      const char* ka1 = k_lds + cb + row128 + c1;
      const char* va0 = v_lds + cb + row128 + c0;
      const char* va1 = v_lds + cb + row128 + c1;

      // S^T = K Q^T : A = K (m = kv), B = Q (n = q). Lane: q = l15,
      // kv = n*16 + l4*4 + r.
      f32x4 s[4];
      __builtin_amdgcn_s_setprio(1);
#pragma unroll
      for (int n = 0; n < 4; ++n) {
        s16x8 kf0 = *(const s16x8*)(ka0 + n * 2048);
        s16x8 kf1 = *(const s16x8*)(ka1 + n * 2048);
        f32x4 z = z4;
        z = mfma_bf16(kf0, qf0, z);
        z = mfma_bf16(kf1, qf1, z);
        s[n] = z;
      }
      __builtin_amdgcn_s_setprio(0);

      if (kt == qi) {                       // causal mask, diagonal tile only
        int ql = w * 16 + l15;
#pragma unroll
        for (int n = 0; n < 4; ++n)
#pragma unroll
          for (int r = 0; r < 4; ++r)
            if ((n * 16 + l4 * 4 + r) > ql) s[n][r] = -3.0e38f;
      }

      // in-lane partial max over this lane's 16 kv values
      float t0 = fmaxf(fmaxf(s[0][0], s[0][1]), fmaxf(s[0][2], s[0][3]));
      float t1 = fmaxf(fmaxf(s[1][0], s[1][1]), fmaxf(s[1][2], s[1][3]));
      float t2 = fmaxf(fmaxf(s[2][0], s[2][1]), fmaxf(s[2][2], s[2][3]));
      float t3 = fmaxf(fmaxf(s[3][0], s[3][1]), fmaxf(s[3][2], s[3][3]));
      float tm = fmaxf(fmaxf(t0, t1), fmaxf(t2, t3));
      // reduce across the 4 l4-groups: xor16 (intra-32) + bpermute (cross-32)
      tm = fmaxf(tm, __shfl_xor(tm, 16));
      tm = fmaxf(tm, __int_as_float(__builtin_amdgcn_ds_bpermute(
                         bperm_addr, __float_as_int(tm))));

      // defer-max (T13): only rescale when the max grew by more than THR
      if (!__all((tm - m_r) * SC2 <= 8.0f)) {
        float m_n = fmaxf(m_r, tm);
        float corr = __builtin_amdgcn_exp2f((m_r - m_n) * SC2);
        m_r = m_n;
        // broadcast corr (per q-row l15) to accumulator layout q = l4*4+r
        *(float*)(pw + 256 + l15 * 4) = corr;
        asm volatile("s_waitcnt lgkmcnt(0)" ::: "memory");
        __builtin_amdgcn_sched_barrier(0);
        float corr4[4];
#pragma unroll
        for (int r = 0; r < 4; ++r)
          corr4[r] = *(const float*)(pw + 256 + (l4 * 4 + r) * 4);
#pragma unroll
        for (int r = 0; r < 4; ++r) {
          acc_l[r] *= corr4[r];
#pragma unroll
          for (int dc = 0; dc < 4; ++dc) acc_o[dc][r] *= corr4[r];
        }
      }

      // P = exp2(s*SC2 - m*SC2), bounded by 2^8 -> truncation pack -> b64
      float msc = m_r * SC2;
      {
        float p0 = __builtin_amdgcn_exp2f(fmaf(s[0][0], SC2, -msc));
        float p1 = __builtin_amdgcn_exp2f(fmaf(s[0][1], SC2, -msc));
        float p2 = __builtin_amdgcn_exp2f(fmaf(s[0][2], SC2, -msc));
        float p3 = __builtin_amdgcn_exp2f(fmaf(s[0][3], SC2, -msc));
        u32x2 pr;
        pr[0] = (__float_as_uint(p1) & 0xffff0000u) | (__float_as_uint(p0) >> 16);
        pr[1] = (__float_as_uint(p3) & 0xffff0000u) | (__float_as_uint(p2) >> 16);
        *(u32x2*)pwr0 = pr;
        p0 = __builtin_amdgcn_exp2f(fmaf(s[1][0], SC2, -msc));
        p1 = __builtin_amdgcn_exp2f(fmaf(s[1][1], SC2, -msc));
        p2 = __builtin_amdgcn_exp2f(fmaf(s[1][2], SC2, -msc));
        p3 = __builtin_amdgcn_exp2f(fmaf(s[1][3], SC2, -msc));
        pr[0] = (__float_as_uint(p1) & 0xffff0000u) | (__float_as_uint(p0) >> 16);
        pr[1] = (__float_as_uint(p3) & 0xffff0000u) | (__float_as_uint(p2) >> 16);
        *(u32x2*)pwr1 = pr;
        p0 = __builtin_amdgcn_exp2f(fmaf(s[2][0], SC2, -msc));
        p1 = __builtin_amdgcn_exp2f(fmaf(s[2][1], SC2, -msc));
        p2 = __builtin_amdgcn_exp2f(fmaf(s[2][2], SC2, -msc));
        p3 = __builtin_amdgcn_exp2f(fmaf(s[2][3], SC2, -msc));
        pr[0] = (__float_as_uint(p1) & 0xffff0000u) | (__float_as_uint(p0) >> 16);
        pr[1] = (__float_as_uint(p3) & 0xffff0000u) | (__float_as_uint(p2) >> 16);
        *(u32x2*)pwr2 = pr;
        p0 = __builtin_amdgcn_exp2f(fmaf(s[3][0], SC2, -msc));
        p1 = __builtin_amdgcn_exp2f(fmaf(s[3][1], SC2, -msc));
        p2 = __builtin_amdgcn_exp2f(fmaf(s[3][2], SC2, -msc));
        p3 = __builtin_amdgcn_exp2f(fmaf(s[3][3], SC2, -msc));
        pr[0] = (__float_as_uint(p1) & 0xffff0000u) | (__float_as_uint(p0) >> 16);
        pr[1] = (__float_as_uint(p3) & 0xffff0000u) | (__float_as_uint(p2) >> 16);
        *(u32x2*)pwr3 = pr;
      }

      // P writes are wave-private; DS pipe is in-order per wave, just drain
      asm volatile("s_waitcnt lgkmcnt(0)" ::: "memory");
      __builtin_amdgcn_sched_barrier(0);

      // O += P V ; denominator += P * ones
      __builtin_amdgcn_s_setprio(1);
      {
        s16x8 pf0 = *(const s16x8*)prd0;
        s16x8 pf1 = *(const s16x8*)prd1;
        acc_l = mfma_bf16(pf0, onesf, acc_l);
        acc_l = mfma_bf16(pf1, onesf, acc_l);
#pragma unroll
        for (int dc = 0; dc < 4; ++dc) {
          s16x8 vf0 = *(const s16x8*)(va0 + dc * 2048);
          s16x8 vf1 = *(const s16x8*)(va1 + dc * 2048);
          acc_o[dc] = mfma_bf16(pf0, vf0, acc_o[dc]);
          acc_o[dc] = mfma_bf16(pf1, vf1, acc_o[dc]);
        }
      }
      __builtin_amdgcn_s_setprio(0);
      cur ^= 1;
    }

    // normalize + write ctx (bf16)
#pragma unroll
    for (int r = 0; r < 4; ++r) {
      int qg = qi * 64 + w * 16 + l4 * 4 + r;
      float inv = 1.0f / acc_l[r];
      size_t base = (size_t)(b * TLEN + qg) * CD + h * HDIM;
#pragma unroll
      for (int dc = 0; dc < 4; ++dc)
        ctx[base + dc * 16 + l15] = f2bf(acc_o[dc][r] * inv);
    }
  }
}

// ---------------- launch ----------------
extern "C" void kernel_launch(void* const* d_in, const int* in_sizes, int n_in,
                              void* d_out, int out_size, void* d_ws, size_t ws_size,
                              hipStream_t stream) {
  const float* X  = (const float*)d_in[0];   // [4,2048,1024]
  const float* Wq = (const float*)d_in[1];   // [3072,1024]
  const float* bq = (const float*)d_in[2];   // [3072]
  const float* Wo = (const float*)d_in[3];   // [1024,1024]
  const float* bo = (const float*)d_in[4];   // [1024]
  float* out = (float*)d_out;

  char* ws = (char*)d_ws;
  unsigned short* Xb  = (unsigned short*)ws;                       // 16.78 MB
  unsigned short* Wqb = (unsigned short*)(ws + 16777216);          //  6.29 MB
  unsigned short* Wob = (unsigned short*)(ws + 23068672);          //  2.10 MB
  unsigned short* QK  = (unsigned short*)(ws + 25165824);          // 33.55 MB
  unsigned short* Vt  = (unsigned short*)(ws + 58720256);          // 16.78 MB
  unsigned short* Ctx = Xb;   // alias: Xb dead after QKV GEMM     // total 75.5 MB

  cvt_bf16<<<4096, 256, 0, stream>>>(X, Xb);
  cvt_bf16<<<1536, 256, 0, stream>>>(Wq, Wqb);
  cvt_bf16<<<512, 256, 0, stream>>>(Wo, Wob);

  gemm_bt<1><<<dim3(24, 64), 256, 0, stream>>>(Xb, Wqb, bq, nullptr, QK, Vt,
                                               8192, 3072, 1024);
  attn_fwd<<<dim3(16, 64), 256, 0, stream>>>(QK, Vt, Ctx);
  gemm_bt<0><<<dim3(8, 64), 256, 0, stream>>>(Ctx, Wob, bo, out, nullptr, nullptr,
                                              8192, 1024, 1024);
}

// Round 7
// 173.535 us; speedup vs baseline: 1.8417x; 1.1500x over previous
//
#include <hip/hip_runtime.h>
#include <hip/hip_bf16.h>
#include <stdint.h>

// Problem constants
#define TLEN 2048
#define NHEAD 16
#define CD 1024
#define HDIM 64

typedef __attribute__((ext_vector_type(4))) float f32x4;
typedef __attribute__((ext_vector_type(8))) short s16x8;
typedef __attribute__((ext_vector_type(8))) unsigned short u16x8;
typedef __attribute__((ext_vector_type(4))) unsigned short u16x4;
typedef __attribute__((ext_vector_type(2))) unsigned int u32x2;

typedef __attribute__((address_space(1))) const unsigned int global_u32;
typedef __attribute__((address_space(3))) unsigned int lds_u32;

__device__ __forceinline__ void gl_lds16(const void* g, void* l) {
  __builtin_amdgcn_global_load_lds((global_u32*)g, (lds_u32*)l, 16, 0, 0);
}

__device__ __forceinline__ unsigned short f2bf(float x) {
  unsigned int u = __float_as_uint(x);
  u += 0x7fffu + ((u >> 16) & 1u);   // RTNE; inputs finite
  return (unsigned short)(u >> 16);
}

__device__ __forceinline__ f32x4 mfma_bf16(s16x8 a, s16x8 b, f32x4 c) {
  return __builtin_amdgcn_mfma_f32_16x16x32_bf16(a, b, c, 0, 0, 0);
}

// ---------------- fp32 -> bf16 cast, merged (X | Wq | Wo) ----------------
__global__ __launch_bounds__(256) void cvt_all(
    const float* __restrict__ X, const float* __restrict__ Wq,
    const float* __restrict__ Wo, unsigned short* __restrict__ Xb,
    unsigned short* __restrict__ Wqb, unsigned short* __restrict__ Wob) {
  int blk = blockIdx.x;
  const float* src;
  unsigned short* dst;
  int base;
  if (blk < 4096) { src = X;  dst = Xb;  base = blk; }
  else if (blk < 5632) { src = Wq; dst = Wqb; base = blk - 4096; }
  else { src = Wo; dst = Wob; base = blk - 5632; }
  int i = (base * 256 + threadIdx.x) * 8;
  float4 a = *(const float4*)(src + i);
  float4 b = *(const float4*)(src + i + 4);
  u16x8 o;
  o[0] = f2bf(a.x); o[1] = f2bf(a.y); o[2] = f2bf(a.z); o[3] = f2bf(a.w);
  o[4] = f2bf(b.x); o[5] = f2bf(b.y); o[6] = f2bf(b.z); o[7] = f2bf(b.w);
  *(u16x8*)(dst + i) = o;
}

// ---------------- GEMM: C[M][N] = A[M][K] * Bw[N][K]^T + bias ----------------
#define BM 128
#define BN 128
#define BKG 64

template <int SPLIT>
__global__ __launch_bounds__(256) void gemm_bt(
    const unsigned short* __restrict__ A, const unsigned short* __restrict__ Bw,
    const float* __restrict__ bias, float* __restrict__ Cf,
    unsigned short* __restrict__ qk_out, unsigned short* __restrict__ vt_out,
    int M, int N, int K) {
  __shared__ char lds[(BM + BN) * BKG * 2];   // 32 KiB
  char* aL = lds;
  char* bL = lds + BM * BKG * 2;
  const int tid = threadIdx.x;
  const int w = tid >> 6, l = tid & 63, l15 = l & 15, l4 = l >> 4;
  const int wr = w >> 1, wc = w & 1;

  // T1: XCD-aware flat swizzle (nwg % 8 == 0 for both launches)
  const int nbx = gridDim.x;
  const int nwg = nbx * gridDim.y;
  int f = blockIdx.y * nbx + blockIdx.x;
  f = (f & 7) * (nwg >> 3) + (f >> 3);
  const int brow = (f / nbx) * BM, bcol = (f % nbx) * BN;

  f32x4 z4 = {0.f, 0.f, 0.f, 0.f};
  f32x4 acc[4][4];
#pragma unroll
  for (int m = 0; m < 4; ++m)
#pragma unroll
    for (int n = 0; n < 4; ++n) acc[m][n] = z4;

  const unsigned short* Ab = A + (size_t)brow * K;
  const unsigned short* Bb = Bw + (size_t)bcol * K;

  for (int k0 = 0; k0 < K; k0 += BKG) {
    __syncthreads();
#pragma unroll
    for (int i = 0; i < 4; ++i) {
      int ch = i * 256 + tid;
      int r = ch >> 3, c = ch & 7;
      int cs = (c ^ (r & 7)) * 8;
      gl_lds16(Ab + (size_t)r * K + k0 + cs, aL + ch * 16);
      gl_lds16(Bb + (size_t)r * K + k0 + cs, bL + ch * 16);
    }
    __syncthreads();
#pragma unroll
    for (int kk = 0; kk < 2; ++kk) {
      s16x8 af[4], bfr[4];
#pragma unroll
      for (int m = 0; m < 4; ++m) {
        int r = wr * 64 + m * 16 + l15;
        af[m] = *(const s16x8*)(aL + r * (BKG * 2) +
                                ((kk * 64 + l4 * 16) ^ ((r & 7) << 4)));
      }
#pragma unroll
      for (int n = 0; n < 4; ++n) {
        int r = wc * 64 + n * 16 + l15;
        bfr[n] = *(const s16x8*)(bL + r * (BKG * 2) +
                                 ((kk * 64 + l4 * 16) ^ ((r & 7) << 4)));
      }
#pragma unroll
      for (int m = 0; m < 4; ++m)
#pragma unroll
        for (int n = 0; n < 4; ++n) acc[m][n] = mfma_bf16(af[m], bfr[n], acc[m][n]);
    }
  }

#pragma unroll
  for (int m = 0; m < 4; ++m) {
    int row0 = brow + wr * 64 + m * 16 + l4 * 4;
#pragma unroll
    for (int n = 0; n < 4; ++n) {
      int col = bcol + wc * 64 + n * 16 + l15;
      float bs = bias[col];
      if (SPLIT == 0) {
#pragma unroll
        for (int r = 0; r < 4; ++r)
          Cf[(size_t)(row0 + r) * N + col] = acc[m][n][r] + bs;
      } else {
        if (col < 2 * CD) {
#pragma unroll
          for (int r = 0; r < 4; ++r)
            qk_out[(size_t)(row0 + r) * (2 * CD) + col] = f2bf(acc[m][n][r] + bs);
        } else {
          int cc = col - 2 * CD;
          int b_ = row0 >> 11;
          int t = row0 & (TLEN - 1);
          u16x4 pk;
#pragma unroll
          for (int r = 0; r < 4; ++r) pk[r] = f2bf(acc[m][n][r] + bs);
          *(u16x4*)(vt_out + (size_t)(b_ * CD + cc) * TLEN + t) = pk;
        }
      }
    }
  }
}

// ---------------- flash attention (unpaired, 5 blocks/CU) --------------------
// 2048 blocks (32 q-slots x 64 bh), one q-tile each, longest-first
// (qi = 31 - fblk>>6) so short blocks backfill. XCD decode keeps 8 bh per
// XCD L2. LDS 32KB -> 5 blocks/CU. K double-buffered via global_load_lds;
// V single-buffered via reg-staging (T14): V(kt+1)->VGPR late in iter kt,
// ds_write into v_lds between BAR1/BAR2 of iter kt+1 (lgkm drain + barrier
// for cross-wave visibility). Swapped S^T = mfma(K,Q) softmax in-register.
__global__ __launch_bounds__(256) void attn_fwd(
    const unsigned short* __restrict__ qk,   // [B*T][2048] bf16: Q | K
    const unsigned short* __restrict__ vt,   // [B*H*64][2048] = V^T per head
    unsigned short* __restrict__ ctx) {      // [B*T][1024]
  __shared__ char k_lds[2 * 64 * 128];      // K tiles [kv][d], swizzled, dbuf
  __shared__ char v_lds[64 * 128];          // V^T tile [d][kv], swizzled
  __shared__ char p_lds[4 * 16 * 128];      // per-wave P [16 q][64 kv], swizzled

  const int fblk = blockIdx.y * 32 + blockIdx.x;
  const int xcd = fblk & 7;
  const int bhi = (fblk >> 3) & 7;
  const int qi = 31 - (fblk >> 6);           // longest blocks dispatch first
  const int bh = xcd * 8 + bhi;
  const int b = bh >> 4, h = bh & 15;
  const int tid = threadIdx.x;
  const int w = tid >> 6, l = tid & 63, l15 = l & 15, l4 = l >> 4;
  const int nt = qi + 1;

  const unsigned short* Kg = qk + (size_t)b * TLEN * (2 * CD) + CD + h * HDIM;
  const unsigned short* Vg = vt + (size_t)bh * HDIM * TLEN;

  const float SC2 = 0.18033688011112042f;   // (1/sqrt(64)) * log2(e)
  char* pw = p_lds + w * 2048;              // wave-private 16x128B region

  // ---- loop-invariant address registers ----
  const int sw = (l15 & 7) << 4;
  const int c0 = (l4 * 16) ^ sw;
  const int c1 = (64 + l4 * 16) ^ sw;
  const int row128 = l15 * 128;
  const char* prd0 = pw + row128 + c0;
  const char* prd1 = pw + row128 + c1;
  char* pwr0 = pw + row128 + ((0 * 32 + l4 * 8) ^ sw);
  char* pwr1 = pw + row128 + ((1 * 32 + l4 * 8) ^ sw);
  char* pwr2 = pw + row128 + ((2 * 32 + l4 * 8) ^ sw);
  char* pwr3 = pw + row128 + ((3 * 32 + l4 * 8) ^ sw);
  const int ch0 = tid, ch1 = 256 + tid;
  const int ldsoff0 = ch0 * 16, ldsoff1 = ch1 * 16;
  const int r0 = ch0 >> 3, r1 = ch1 >> 3;
  const int cs0 = ((ch0 & 7) ^ (r0 & 7)) * 8;
  const int cs1 = ((ch1 & 7) ^ (r1 & 7)) * 8;
  const int bperm_addr = (l ^ 32) << 2;

  s16x8 onesf;                              // bf16 1.0 broadcast B-fragment
#pragma unroll
  for (int j = 0; j < 8; ++j) onesf[j] = (short)0x3F80;

  f32x4 z4 = {0.f, 0.f, 0.f, 0.f};

  // Q fragments (B-operand): col q = l15, k: d = l4*8 + j
  const unsigned short* qrow =
      qk + (size_t)(b * TLEN + qi * 64 + w * 16 + l15) * (2 * CD) + h * HDIM;
  s16x8 qf0 = *(const s16x8*)(qrow + l4 * 8);
  s16x8 qf1 = *(const s16x8*)(qrow + 32 + l4 * 8);

  f32x4 acc_o[4];
#pragma unroll
  for (int dc = 0; dc < 4; ++dc) acc_o[dc] = z4;
  f32x4 acc_l = z4;                         // softmax denominator (ones-MFMA)
  float m_r = -3.0e38f;

  // running global staging pointers (bytes), tile 0
  const char* gk0 = (const char*)Kg + r0 * 4096 + cs0 * 2;
  const char* gk1 = (const char*)Kg + r1 * 4096 + cs1 * 2;
  const char* gv0 = (const char*)Vg + r0 * 4096 + cs0 * 2;
  const char* gv1 = (const char*)Vg + r1 * 4096 + cs1 * 2;

  // prologue: K(0) -> k_lds buf0 (DMA); V(0) -> regs
  gl_lds16(gk0, k_lds + ldsoff0);
  gl_lds16(gk1, k_lds + ldsoff1);
  s16x8 vstg0 = *(const s16x8*)gv0;
  s16x8 vstg1 = *(const s16x8*)gv1;
  int cur = 0;

  for (int kt = 0; kt < nt; ++kt) {
    __builtin_amdgcn_s_barrier();           // all waves done PV(kt-1)/QK(kt-1)
    __builtin_amdgcn_sched_barrier(0);
    // everything outstanding was issued >=1 iteration ago
    asm volatile("s_waitcnt vmcnt(0)" ::: "memory");
    // V(kt): regs -> LDS (single buffer)
    *(s16x8*)(v_lds + ldsoff0) = vstg0;
    *(s16x8*)(v_lds + ldsoff1) = vstg1;
    if (kt + 1 < nt) {                      // clamp: last iter reuses addrs
      gk0 += 262144; gk1 += 262144; gv0 += 128; gv1 += 128;
    }
    {                                       // K(kt+1) -> other K buffer
      int nb = (cur ^ 1) << 13;
      gl_lds16(gk0, k_lds + nb + ldsoff0);
      gl_lds16(gk1, k_lds + nb + ldsoff1);
    }
    asm volatile("s_waitcnt lgkmcnt(0)" ::: "memory");  // V writes landed
    __builtin_amdgcn_sched_barrier(0);
    __builtin_amdgcn_s_barrier();           // K(kt) + V(kt) visible to all
    __builtin_amdgcn_sched_barrier(0);

    const int cb = cur << 13;
    const char* ka0 = k_lds + cb + row128 + c0;
    const char* ka1 = k_lds + cb + row128 + c1;

    // S^T = K Q^T : lane q = l15, kv = n*16 + l4*4 + r
    f32x4 s[4];
    __builtin_amdgcn_s_setprio(1);
#pragma unroll
    for (int n = 0; n < 4; ++n) {
      s16x8 kf0 = *(const s16x8*)(ka0 + n * 2048);
      s16x8 kf1 = *(const s16x8*)(ka1 + n * 2048);
      f32x4 z = z4;
      z = mfma_bf16(kf0, qf0, z);
      z = mfma_bf16(kf1, qf1, z);
      s[n] = z;
    }
    __builtin_amdgcn_s_setprio(0);

    if (kt == qi) {                         // causal mask, diagonal tile only
      int ql = w * 16 + l15;
#pragma unroll
      for (int n = 0; n < 4; ++n)
#pragma unroll
        for (int r = 0; r < 4; ++r)
          if ((n * 16 + l4 * 4 + r) > ql) s[n][r] = -3.0e38f;
    }

    // in-lane partial max over this lane's 16 kv values
    float t0 = fmaxf(fmaxf(s[0][0], s[0][1]), fmaxf(s[0][2], s[0][3]));
    float t1 = fmaxf(fmaxf(s[1][0], s[1][1]), fmaxf(s[1][2], s[1][3]));
    float t2 = fmaxf(fmaxf(s[2][0], s[2][1]), fmaxf(s[2][2], s[2][3]));
    float t3 = fmaxf(fmaxf(s[3][0], s[3][1]), fmaxf(s[3][2], s[3][3]));
    float tm = fmaxf(fmaxf(t0, t1), fmaxf(t2, t3));
    tm = fmaxf(tm, __shfl_xor(tm, 16));
    tm = fmaxf(tm, __int_as_float(__builtin_amdgcn_ds_bpermute(
                       bperm_addr, __float_as_int(tm))));

    // defer-max (T13): only rescale when the max grew by more than THR
    if (!__all((tm - m_r) * SC2 <= 8.0f)) {
      float m_n = fmaxf(m_r, tm);
      float corr = __builtin_amdgcn_exp2f((m_r - m_n) * SC2);
      m_r = m_n;
      *(float*)(pw + 256 + l15 * 4) = corr;
      asm volatile("s_waitcnt lgkmcnt(0)" ::: "memory");
      __builtin_amdgcn_sched_barrier(0);
      float corr4[4];
#pragma unroll
      for (int r = 0; r < 4; ++r)
        corr4[r] = *(const float*)(pw + 256 + (l4 * 4 + r) * 4);
#pragma unroll
      for (int r = 0; r < 4; ++r) {
        acc_l[r] *= corr4[r];
#pragma unroll
        for (int dc = 0; dc < 4; ++dc) acc_o[dc][r] *= corr4[r];
      }
    }

    // P = exp2(s*SC2 - m*SC2), bounded by 2^8 -> truncation pack -> b64
    float msc = m_r * SC2;
#pragma unroll
    for (int n = 0; n < 4; ++n) {
      float p0 = __builtin_amdgcn_exp2f(fmaf(s[n][0], SC2, -msc));
      float p1 = __builtin_amdgcn_exp2f(fmaf(s[n][1], SC2, -msc));
      float p2 = __builtin_amdgcn_exp2f(fmaf(s[n][2], SC2, -msc));
      float p3 = __builtin_amdgcn_exp2f(fmaf(s[n][3], SC2, -msc));
      u32x2 pr;
      pr[0] = (__float_as_uint(p1) & 0xffff0000u) | (__float_as_uint(p0) >> 16);
      pr[1] = (__float_as_uint(p3) & 0xffff0000u) | (__float_as_uint(p2) >> 16);
      char* dst = (n == 0) ? pwr0 : (n == 1) ? pwr1 : (n == 2) ? pwr2 : pwr3;
      *(u32x2*)dst = pr;
    }

    // P writes are wave-private; DS pipe is in-order per wave, just drain
    asm volatile("s_waitcnt lgkmcnt(0)" ::: "memory");
    __builtin_amdgcn_sched_barrier(0);

    // late V(kt+1) reg loads: HBM/L2 latency hides under PV + next barrier
    vstg0 = *(const s16x8*)gv0;
    vstg1 = *(const s16x8*)gv1;
    __builtin_amdgcn_sched_barrier(0);

    // O += P V ; denominator += P * ones
    __builtin_amdgcn_s_setprio(1);
    {
      s16x8 pf0 = *(const s16x8*)prd0;
      s16x8 pf1 = *(const s16x8*)prd1;
      acc_l = mfma_bf16(pf0, onesf, acc_l);
      acc_l = mfma_bf16(pf1, onesf, acc_l);
#pragma unroll
      for (int dc = 0; dc < 4; ++dc) {
        s16x8 vf0 = *(const s16x8*)(v_lds + dc * 2048 + row128 + c0);
        s16x8 vf1 = *(const s16x8*)(v_lds + dc * 2048 + row128 + c1);
        acc_o[dc] = mfma_bf16(pf0, vf0, acc_o[dc]);
        acc_o[dc] = mfma_bf16(pf1, vf1, acc_o[dc]);
      }
    }
    __builtin_amdgcn_s_setprio(0);
    cur ^= 1;
  }

  // normalize + write ctx (bf16)
#pragma unroll
  for (int r = 0; r < 4; ++r) {
    int qg = qi * 64 + w * 16 + l4 * 4 + r;
    float inv = 1.0f / acc_l[r];
    size_t base = (size_t)(b * TLEN + qg) * CD + h * HDIM;
#pragma unroll
    for (int dc = 0; dc < 4; ++dc)
      ctx[base + dc * 16 + l15] = f2bf(acc_o[dc][r] * inv);
  }
}

// ---------------- launch ----------------
extern "C" void kernel_launch(void* const* d_in, const int* in_sizes, int n_in,
                              void* d_out, int out_size, void* d_ws, size_t ws_size,
                              hipStream_t stream) {
  const float* X  = (const float*)d_in[0];   // [4,2048,1024]
  const float* Wq = (const float*)d_in[1];   // [3072,1024]
  const float* bq = (const float*)d_in[2];   // [3072]
  const float* Wo = (const float*)d_in[3];   // [1024,1024]
  const float* bo = (const float*)d_in[4];   // [1024]
  float* out = (float*)d_out;

  char* ws = (char*)d_ws;
  unsigned short* Xb  = (unsigned short*)ws;                       // 16.78 MB
  unsigned short* Wqb = (unsigned short*)(ws + 16777216);          //  6.29 MB
  unsigned short* Wob = (unsigned short*)(ws + 23068672);          //  2.10 MB
  unsigned short* QK  = (unsigned short*)(ws + 25165824);          // 33.55 MB
  unsigned short* Vt  = (unsigned short*)(ws + 58720256);          // 16.78 MB
  unsigned short* Ctx = Xb;   // alias: Xb dead after QKV GEMM     // total 75.5 MB

  cvt_all<<<6144, 256, 0, stream>>>(X, Wq, Wo, Xb, Wqb, Wob);

  gemm_bt<1><<<dim3(24, 64), 256, 0, stream>>>(Xb, Wqb, bq, nullptr, QK, Vt,
                                               8192, 3072, 1024);
  attn_fwd<<<dim3(32, 64), 256, 0, stream>>>(QK, Vt, Ctx);
  gemm_bt<0><<<dim3(8, 64), 256, 0, stream>>>(Ctx, Wob, bo, out, nullptr, nullptr,
                                              8192, 1024, 1024);
}

// Round 8
// 171.926 us; speedup vs baseline: 1.8589x; 1.0094x over previous
//
#include <hip/hip_runtime.h>
#include <hip/hip_bf16.h>
#include <stdint.h>

// Problem constants
#define TLEN 2048
#define NHEAD 16
#define CD 1024
#define HDIM 64

typedef __attribute__((ext_vector_type(4))) float f32x4;
typedef __attribute__((ext_vector_type(8))) short s16x8;
typedef __attribute__((ext_vector_type(8))) unsigned short u16x8;
typedef __attribute__((ext_vector_type(4))) unsigned short u16x4;
typedef __attribute__((ext_vector_type(2))) unsigned int u32x2;

typedef __attribute__((address_space(1))) const unsigned int global_u32;
typedef __attribute__((address_space(3))) unsigned int lds_u32;

__device__ __forceinline__ void gl_lds16(const void* g, void* l) {
  __builtin_amdgcn_global_load_lds((global_u32*)g, (lds_u32*)l, 16, 0, 0);
}

__device__ __forceinline__ unsigned short f2bf(float x) {
  unsigned int u = __float_as_uint(x);
  u += 0x7fffu + ((u >> 16) & 1u);   // RTNE; inputs finite
  return (unsigned short)(u >> 16);
}

__device__ __forceinline__ f32x4 mfma_bf16(s16x8 a, s16x8 b, f32x4 c) {
  return __builtin_amdgcn_mfma_f32_16x16x32_bf16(a, b, c, 0, 0, 0);
}

// ---------------- fp32 -> bf16 cast, merged (X | Wq | Wo) ----------------
__global__ __launch_bounds__(256) void cvt_all(
    const float* __restrict__ X, const float* __restrict__ Wq,
    const float* __restrict__ Wo, unsigned short* __restrict__ Xb,
    unsigned short* __restrict__ Wqb, unsigned short* __restrict__ Wob) {
  int blk = blockIdx.x;
  const float* src;
  unsigned short* dst;
  int base;
  if (blk < 4096) { src = X;  dst = Xb;  base = blk; }
  else if (blk < 5632) { src = Wq; dst = Wqb; base = blk - 4096; }
  else { src = Wo; dst = Wob; base = blk - 5632; }
  int i = (base * 256 + threadIdx.x) * 8;
  float4 a = *(const float4*)(src + i);
  float4 b = *(const float4*)(src + i + 4);
  u16x8 o;
  o[0] = f2bf(a.x); o[1] = f2bf(a.y); o[2] = f2bf(a.z); o[3] = f2bf(a.w);
  o[4] = f2bf(b.x); o[5] = f2bf(b.y); o[6] = f2bf(b.z); o[7] = f2bf(b.w);
  *(u16x8*)(dst + i) = o;
}

// ---------------- GEMM: C[M][N] = A[M][K] * Bw[N][K]^T + bias ----------------
#define BM 128
#define BN 128
#define BKG 64

template <int SPLIT>
__global__ __launch_bounds__(256) void gemm_bt(
    const unsigned short* __restrict__ A, const unsigned short* __restrict__ Bw,
    const float* __restrict__ bias, float* __restrict__ Cf,
    unsigned short* __restrict__ qk_out, unsigned short* __restrict__ vt_out,
    int M, int N, int K) {
  __shared__ char lds[(BM + BN) * BKG * 2];   // 32 KiB
  char* aL = lds;
  char* bL = lds + BM * BKG * 2;
  const int tid = threadIdx.x;
  const int w = tid >> 6, l = tid & 63, l15 = l & 15, l4 = l >> 4;
  const int wr = w >> 1, wc = w & 1;

  // T1: XCD-aware flat swizzle (nwg % 8 == 0 for both launches)
  const int nbx = gridDim.x;
  const int nwg = nbx * gridDim.y;
  int f = blockIdx.y * nbx + blockIdx.x;
  f = (f & 7) * (nwg >> 3) + (f >> 3);
  const int brow = (f / nbx) * BM, bcol = (f % nbx) * BN;

  f32x4 z4 = {0.f, 0.f, 0.f, 0.f};
  f32x4 acc[4][4];
#pragma unroll
  for (int m = 0; m < 4; ++m)
#pragma unroll
    for (int n = 0; n < 4; ++n) acc[m][n] = z4;

  const unsigned short* Ab = A + (size_t)brow * K;
  const unsigned short* Bb = Bw + (size_t)bcol * K;

  for (int k0 = 0; k0 < K; k0 += BKG) {
    __syncthreads();
#pragma unroll
    for (int i = 0; i < 4; ++i) {
      int ch = i * 256 + tid;
      int r = ch >> 3, c = ch & 7;
      int cs = (c ^ (r & 7)) * 8;
      gl_lds16(Ab + (size_t)r * K + k0 + cs, aL + ch * 16);
      gl_lds16(Bb + (size_t)r * K + k0 + cs, bL + ch * 16);
    }
    __syncthreads();
#pragma unroll
    for (int kk = 0; kk < 2; ++kk) {
      s16x8 af[4], bfr[4];
#pragma unroll
      for (int m = 0; m < 4; ++m) {
        int r = wr * 64 + m * 16 + l15;
        af[m] = *(const s16x8*)(aL + r * (BKG * 2) +
                                ((kk * 64 + l4 * 16) ^ ((r & 7) << 4)));
      }
#pragma unroll
      for (int n = 0; n < 4; ++n) {
        int r = wc * 64 + n * 16 + l15;
        bfr[n] = *(const s16x8*)(bL + r * (BKG * 2) +
                                 ((kk * 64 + l4 * 16) ^ ((r & 7) << 4)));
      }
#pragma unroll
      for (int m = 0; m < 4; ++m)
#pragma unroll
        for (int n = 0; n < 4; ++n) acc[m][n] = mfma_bf16(af[m], bfr[n], acc[m][n]);
    }
  }

#pragma unroll
  for (int m = 0; m < 4; ++m) {
    int row0 = brow + wr * 64 + m * 16 + l4 * 4;
#pragma unroll
    for (int n = 0; n < 4; ++n) {
      int col = bcol + wc * 64 + n * 16 + l15;
      float bs = bias[col];
      if (SPLIT == 0) {
#pragma unroll
        for (int r = 0; r < 4; ++r)
          Cf[(size_t)(row0 + r) * N + col] = acc[m][n][r] + bs;
      } else {
        if (col < 2 * CD) {
#pragma unroll
          for (int r = 0; r < 4; ++r)
            qk_out[(size_t)(row0 + r) * (2 * CD) + col] = f2bf(acc[m][n][r] + bs);
        } else {
          int cc = col - 2 * CD;
          int b_ = row0 >> 11;
          int t = row0 & (TLEN - 1);
          u16x4 pk;
#pragma unroll
          for (int r = 0; r < 4; ++r) pk[r] = f2bf(acc[m][n][r] + bs);
          *(u16x4*)(vt_out + (size_t)(b_ * CD + cc) * TLEN + t) = pk;
        }
      }
    }
  }
}

// ---------------- flash attention (16 KB LDS, 7 blocks/CU) -------------------
// 2048 blocks (one q-tile each, longest-first), XCD decode: 8 bh per XCD L2.
// K and V both reg-staged (T14): K/V(t+1)->VGPRs right after the ds_writes of
// tile t, so HBM latency hides under the whole compute phase. Single 8KB LDS
// buffer each. P ALIASES k_lds: safe because (1) BAR(c) after the max-reduce
// guarantees all waves' QK K-reads are done before any P write, and (2)
// BAR(a) guarantees all PV P-reads are done before the next K ds_write.
// Swapped S^T = mfma(K,Q) in-register softmax, defer-max (T13).
__global__ __launch_bounds__(256) void attn_fwd(
    const unsigned short* __restrict__ qk,   // [B*T][2048] bf16: Q | K
    const unsigned short* __restrict__ vt,   // [B*H*64][2048] = V^T per head
    unsigned short* __restrict__ ctx) {      // [B*T][1024]
  __shared__ char k_lds[64 * 128];          // K tile; re-used as P after BAR(c)
  __shared__ char v_lds[64 * 128];          // V^T tile [d][kv], swizzled

  const int fblk = blockIdx.y * 32 + blockIdx.x;
  const int xcd = fblk & 7;
  const int bhi = (fblk >> 3) & 7;
  const int qi = 31 - (fblk >> 6);           // longest blocks dispatch first
  const int bh = xcd * 8 + bhi;
  const int b = bh >> 4, h = bh & 15;
  const int tid = threadIdx.x;
  const int w = tid >> 6, l = tid & 63, l15 = l & 15, l4 = l >> 4;
  const int nt = qi + 1;

  const unsigned short* Kg = qk + (size_t)b * TLEN * (2 * CD) + CD + h * HDIM;
  const unsigned short* Vg = vt + (size_t)bh * HDIM * TLEN;

  const float SC2 = 0.18033688011112042f;   // (1/sqrt(64)) * log2(e)
  char* pw = k_lds + w * 2048;              // wave-private P slice (alias)

  // ---- loop-invariant address registers ----
  const int sw = (l15 & 7) << 4;
  const int c0 = (l4 * 16) ^ sw;
  const int c1 = (64 + l4 * 16) ^ sw;
  const int row128 = l15 * 128;
  const char* prd0 = pw + row128 + c0;
  const char* prd1 = pw + row128 + c1;
  char* pwr0 = pw + row128 + ((0 * 32 + l4 * 8) ^ sw);
  char* pwr1 = pw + row128 + ((1 * 32 + l4 * 8) ^ sw);
  char* pwr2 = pw + row128 + ((2 * 32 + l4 * 8) ^ sw);
  char* pwr3 = pw + row128 + ((3 * 32 + l4 * 8) ^ sw);
  const int ch0 = tid, ch1 = 256 + tid;
  const int ldsoff0 = ch0 * 16, ldsoff1 = ch1 * 16;
  const int r0 = ch0 >> 3, r1 = ch1 >> 3;
  const int cs0 = ((ch0 & 7) ^ (r0 & 7)) * 8;
  const int cs1 = ((ch1 & 7) ^ (r1 & 7)) * 8;
  const int bperm_addr = (l ^ 32) << 2;

  s16x8 onesf;                              // bf16 1.0 broadcast B-fragment
#pragma unroll
  for (int j = 0; j < 8; ++j) onesf[j] = (short)0x3F80;

  f32x4 z4 = {0.f, 0.f, 0.f, 0.f};

  // Q fragments (B-operand): col q = l15, k: d = l4*8 + j
  const unsigned short* qrow =
      qk + (size_t)(b * TLEN + qi * 64 + w * 16 + l15) * (2 * CD) + h * HDIM;
  s16x8 qf0 = *(const s16x8*)(qrow + l4 * 8);
  s16x8 qf1 = *(const s16x8*)(qrow + 32 + l4 * 8);

  f32x4 acc_o[4];
#pragma unroll
  for (int dc = 0; dc < 4; ++dc) acc_o[dc] = z4;
  f32x4 acc_l = z4;                         // softmax denominator (ones-MFMA)
  float m_r = -3.0e38f;

  // running global staging pointers (bytes), tile 0
  const char* gk0 = (const char*)Kg + r0 * 4096 + cs0 * 2;
  const char* gk1 = (const char*)Kg + r1 * 4096 + cs1 * 2;
  const char* gv0 = (const char*)Vg + r0 * 4096 + cs0 * 2;
  const char* gv1 = (const char*)Vg + r1 * 4096 + cs1 * 2;

  // prologue: K(0), V(0) -> regs
  s16x8 kstg0 = *(const s16x8*)gk0;
  s16x8 kstg1 = *(const s16x8*)gk1;
  s16x8 vstg0 = *(const s16x8*)gv0;
  s16x8 vstg1 = *(const s16x8*)gv1;

  for (int kt = 0; kt < nt; ++kt) {
    __builtin_amdgcn_s_barrier();           // BAR(a): all LDS reads of t-1 done
    __builtin_amdgcn_sched_barrier(0);
    asm volatile("s_waitcnt vmcnt(0)" ::: "memory");  // staging regs ready
    // K(t), V(t): regs -> LDS (single buffers; K overwrites dead P(t-1))
    *(s16x8*)(k_lds + ldsoff0) = kstg0;
    *(s16x8*)(k_lds + ldsoff1) = kstg1;
    *(s16x8*)(v_lds + ldsoff0) = vstg0;
    *(s16x8*)(v_lds + ldsoff1) = vstg1;
    if (kt + 1 < nt) {                      // issue K/V(t+1) -> regs (early)
      gk0 += 262144; gk1 += 262144; gv0 += 128; gv1 += 128;
      kstg0 = *(const s16x8*)gk0;
      kstg1 = *(const s16x8*)gk1;
      vstg0 = *(const s16x8*)gv0;
      vstg1 = *(const s16x8*)gv1;
    }
    asm volatile("s_waitcnt lgkmcnt(0)" ::: "memory");  // ds_writes landed
    __builtin_amdgcn_sched_barrier(0);
    __builtin_amdgcn_s_barrier();           // BAR(b): K(t)+V(t) visible
    __builtin_amdgcn_sched_barrier(0);

    const char* ka0 = k_lds + row128 + c0;
    const char* ka1 = k_lds + row128 + c1;

    // S^T = K Q^T : lane q = l15, kv = n*16 + l4*4 + r
    f32x4 s[4];
    __builtin_amdgcn_s_setprio(1);
#pragma unroll
    for (int n = 0; n < 4; ++n) {
      s16x8 kf0 = *(const s16x8*)(ka0 + n * 2048);
      s16x8 kf1 = *(const s16x8*)(ka1 + n * 2048);
      f32x4 z = z4;
      z = mfma_bf16(kf0, qf0, z);
      z = mfma_bf16(kf1, qf1, z);
      s[n] = z;
    }
    __builtin_amdgcn_s_setprio(0);

    if (kt == qi) {                         // causal mask, diagonal tile only
      int ql = w * 16 + l15;
#pragma unroll
      for (int n = 0; n < 4; ++n)
#pragma unroll
        for (int r = 0; r < 4; ++r)
          if ((n * 16 + l4 * 4 + r) > ql) s[n][r] = -3.0e38f;
    }

    // in-lane partial max over this lane's 16 kv values
    float t0 = fmaxf(fmaxf(s[0][0], s[0][1]), fmaxf(s[0][2], s[0][3]));
    float t1 = fmaxf(fmaxf(s[1][0], s[1][1]), fmaxf(s[1][2], s[1][3]));
    float t2 = fmaxf(fmaxf(s[2][0], s[2][1]), fmaxf(s[2][2], s[2][3]));
    float t3 = fmaxf(fmaxf(s[3][0], s[3][1]), fmaxf(s[3][2], s[3][3]));
    float tm = fmaxf(fmaxf(t0, t1), fmaxf(t2, t3));
    tm = fmaxf(tm, __shfl_xor(tm, 16));
    tm = fmaxf(tm, __int_as_float(__builtin_amdgcn_ds_bpermute(
                       bperm_addr, __float_as_int(tm))));

    __builtin_amdgcn_s_barrier();           // BAR(c): all K-reads done ->
    __builtin_amdgcn_sched_barrier(0);      //         k_lds free for P

    // defer-max (T13): only rescale when the max grew by more than THR
    if (!__all((tm - m_r) * SC2 <= 8.0f)) {
      float m_n = fmaxf(m_r, tm);
      float corr = __builtin_amdgcn_exp2f((m_r - m_n) * SC2);
      m_r = m_n;
      *(float*)(pw + 256 + l15 * 4) = corr;
      asm volatile("s_waitcnt lgkmcnt(0)" ::: "memory");
      __builtin_amdgcn_sched_barrier(0);
      float corr4[4];
#pragma unroll
      for (int r = 0; r < 4; ++r)
        corr4[r] = *(const float*)(pw + 256 + (l4 * 4 + r) * 4);
#pragma unroll
      for (int r = 0; r < 4; ++r) {
        acc_l[r] *= corr4[r];
#pragma unroll
        for (int dc = 0; dc < 4; ++dc) acc_o[dc][r] *= corr4[r];
      }
    }

    // P = exp2(s*SC2 - m*SC2), bounded by 2^8 -> truncation pack -> b64
    float msc = m_r * SC2;
#pragma unroll
    for (int n = 0; n < 4; ++n) {
      float p0 = __builtin_amdgcn_exp2f(fmaf(s[n][0], SC2, -msc));
      float p1 = __builtin_amdgcn_exp2f(fmaf(s[n][1], SC2, -msc));
      float p2 = __builtin_amdgcn_exp2f(fmaf(s[n][2], SC2, -msc));
      float p3 = __builtin_amdgcn_exp2f(fmaf(s[n][3], SC2, -msc));
      u32x2 pr;
      pr[0] = (__float_as_uint(p1) & 0xffff0000u) | (__float_as_uint(p0) >> 16);
      pr[1] = (__float_as_uint(p3) & 0xffff0000u) | (__float_as_uint(p2) >> 16);
      char* dst = (n == 0) ? pwr0 : (n == 1) ? pwr1 : (n == 2) ? pwr2 : pwr3;
      *(u32x2*)dst = pr;
    }

    // P writes are wave-private; DS pipe is in-order per wave, just drain
    asm volatile("s_waitcnt lgkmcnt(0)" ::: "memory");
    __builtin_amdgcn_sched_barrier(0);

    // O += P V ; denominator += P * ones
    __builtin_amdgcn_s_setprio(1);
    {
      s16x8 pf0 = *(const s16x8*)prd0;
      s16x8 pf1 = *(const s16x8*)prd1;
      acc_l = mfma_bf16(pf0, onesf, acc_l);
      acc_l = mfma_bf16(pf1, onesf, acc_l);
#pragma unroll
      for (int dc = 0; dc < 4; ++dc) {
        s16x8 vf0 = *(const s16x8*)(v_lds + dc * 2048 + row128 + c0);
        s16x8 vf1 = *(const s16x8*)(v_lds + dc * 2048 + row128 + c1);
        acc_o[dc] = mfma_bf16(pf0, vf0, acc_o[dc]);
        acc_o[dc] = mfma_bf16(pf1, vf1, acc_o[dc]);
      }
    }
    __builtin_amdgcn_s_setprio(0);
  }

  // normalize + write ctx (bf16)
#pragma unroll
  for (int r = 0; r < 4; ++r) {
    int qg = qi * 64 + w * 16 + l4 * 4 + r;
    float inv = 1.0f / acc_l[r];
    size_t base = (size_t)(b * TLEN + qg) * CD + h * HDIM;
#pragma unroll
    for (int dc = 0; dc < 4; ++dc)
      ctx[base + dc * 16 + l15] = f2bf(acc_o[dc][r] * inv);
  }
}

// ---------------- launch ----------------
extern "C" void kernel_launch(void* const* d_in, const int* in_sizes, int n_in,
                              void* d_out, int out_size, void* d_ws, size_t ws_size,
                              hipStream_t stream) {
  const float* X  = (const float*)d_in[0];   // [4,2048,1024]
  const float* Wq = (const float*)d_in[1];   // [3072,1024]
  const float* bq = (const float*)d_in[2];   // [3072]
  const float* Wo = (const float*)d_in[3];   // [1024,1024]
  const float* bo = (const float*)d_in[4];   // [1024]
  float* out = (float*)d_out;

  char* ws = (char*)d_ws;
  unsigned short* Xb  = (unsigned short*)ws;                       // 16.78 MB
  unsigned short* Wqb = (unsigned short*)(ws + 16777216);          //  6.29 MB
  unsigned short* Wob = (unsigned short*)(ws + 23068672);          //  2.10 MB
  unsigned short* QK  = (unsigned short*)(ws + 25165824);          // 33.55 MB
  unsigned short* Vt  = (unsigned short*)(ws + 58720256);          // 16.78 MB
  unsigned short* Ctx = Xb;   // alias: Xb dead after QKV GEMM     // total 75.5 MB

  cvt_all<<<6144, 256, 0, stream>>>(X, Wq, Wo, Xb, Wqb, Wob);

  gemm_bt<1><<<dim3(24, 64), 256, 0, stream>>>(Xb, Wqb, bq, nullptr, QK, Vt,
                                               8192, 3072, 1024);
  attn_fwd<<<dim3(32, 64), 256, 0, stream>>>(QK, Vt, Ctx);
  gemm_bt<0><<<dim3(8, 64), 256, 0, stream>>>(Ctx, Wob, bo, out, nullptr, nullptr,
                                              8192, 1024, 1024);
}